// Round 1
// baseline (2747.225 us; speedup 1.0000x reference)
//
#include <hip/hip_runtime.h>
#include <stdint.h>

// ---------- constants ----------
#define Bn 4
#define Sn 1024
#define Dn 1024
#define Fn 4096
#define En 8
#define Hn 16
#define HDn 64
#define Mn 4096           // B*S tokens
#define OUT0 0
#define LOGOFF 4194304    // B*S*D
#define PROBOFF 4227072   // + B*S*E
#define MEANOFF 4259840   // + B*S*E

typedef __attribute__((ext_vector_type(8))) short short8;
typedef __attribute__((ext_vector_type(4))) float f32x4;
typedef __attribute__((ext_vector_type(4))) unsigned short u16x4;

#define DEV static __device__ __forceinline__

DEV float bf2f(unsigned short u) {
  union { uint32_t i; float f; } x; x.i = ((uint32_t)u) << 16; return x.f;
}
DEV unsigned short f2bf(float f) {
  union { float f; uint32_t i; } x; x.f = f;
  uint32_t r = x.i + 0x7FFFu + ((x.i >> 16) & 1u);
  return (unsigned short)(r >> 16);
}

DEV void gl_lds16(const void* g, void* l) {
  __builtin_amdgcn_global_load_lds((const __attribute__((address_space(1))) void*)g,
                                   (__attribute__((address_space(3))) void*)l,
                                   16, 0, 0);
}

DEV float wsum(float v) { for (int o = 1; o < 64; o <<= 1) v += __shfl_xor(v, o); return v; }
DEV float wmaxr(float v) { for (int o = 1; o < 64; o <<= 1) v = fmaxf(v, __shfl_xor(v, o)); return v; }

DEV float block_sum(float v, float* sred, int t) {
  int w = t >> 6, l = t & 63;
  v = wsum(v);
  __syncthreads();
  if (l == 0) sred[w] = v;
  __syncthreads();
  return sred[0] + sred[1] + sred[2] + sred[3];
}
DEV float block_max(float v, float* sred, int t) {
  int w = t >> 6, l = t & 63;
  v = wmaxr(v);
  __syncthreads();
  if (l == 0) sred[w] = v;
  __syncthreads();
  return fmaxf(fmaxf(sred[0], sred[1]), fmaxf(sred[2], sred[3]));
}

// ---------- GEMM core: C[128 x JT*32] tile, bf16 MFMA 16x16x32, BK=32 ----------
// A: [M][K] bf16 row-major; Bt: [N][K] bf16 row-major (i.e. B transposed, k-contiguous)
template<int JT>   // JT = n-subtiles per wave: 4 -> TN=128, 2 -> TN=64
DEV void gemm_core(const unsigned short* __restrict__ A, const unsigned short* __restrict__ Bt,
                   int K, int m0, int n0,
                   unsigned short* lA, unsigned short* lB, f32x4 (&acc)[4][JT]) {
  const int t = threadIdx.x;
  const int w = t >> 6;
  const int l = t & 63;
  const int lrow = l >> 2;          // 0..15 rows within a 16-row staging chunk
  const int lko  = (l & 3) * 8;     // k offset (ushort units) within row
  const int wm = (w >> 1) * 64;
  const int wn = (w & 1) * (JT * 16);
  const int lm = l & 15;
  const int q  = l >> 4;
  for (int k0 = 0; k0 < K; k0 += 32) {
    { // stage A tile 128x32: 8 wave-insts, wave does rows [w*32, w*32+32)
      int r0 = w * 32 + lrow;
      gl_lds16(A + (size_t)(m0 + r0) * K + k0 + lko, lA + (w * 32) * 32);
      gl_lds16(A + (size_t)(m0 + r0 + 16) * K + k0 + lko, lA + (w * 32 + 16) * 32);
    }
    if (JT == 4) { // stage Bt tile 128x32
      int r0 = w * 32 + lrow;
      gl_lds16(Bt + (size_t)(n0 + r0) * K + k0 + lko, lB + (w * 32) * 32);
      gl_lds16(Bt + (size_t)(n0 + r0 + 16) * K + k0 + lko, lB + (w * 32 + 16) * 32);
    } else {       // 64x32
      int r0 = w * 16 + lrow;
      gl_lds16(Bt + (size_t)(n0 + r0) * K + k0 + lko, lB + (w * 16) * 32);
    }
    __syncthreads();
    short8 af[4], bfr[JT];
#pragma unroll
    for (int i = 0; i < 4; ++i)
      af[i] = *(const short8*)(lA + (wm + i * 16 + lm) * 32 + q * 8);
#pragma unroll
    for (int j = 0; j < JT; ++j)
      bfr[j] = *(const short8*)(lB + (wn + j * 16 + lm) * 32 + q * 8);
#pragma unroll
    for (int i = 0; i < 4; ++i)
#pragma unroll
      for (int j = 0; j < JT; ++j)
        acc[i][j] = __builtin_amdgcn_mfma_f32_16x16x32_bf16(af[i], bfr[j], acc[i][j], 0, 0, 0);
    __syncthreads();
  }
}

#define GEMM_PROLOG(JT)                                         \
  __shared__ __align__(16) unsigned short lA[128 * 32];         \
  __shared__ __align__(16) unsigned short lB[(JT) * 32 * 32];   \
  f32x4 acc[4][JT];                                             \
  _Pragma("unroll") for (int i = 0; i < 4; ++i)                 \
  _Pragma("unroll") for (int j = 0; j < (JT); ++j)              \
      acc[i][j] = (f32x4){0.f, 0.f, 0.f, 0.f};

#define EPI_VARS(JT)                                            \
  const int t = threadIdx.x; const int w = t >> 6;              \
  const int l = t & 63;                                         \
  const int wm = (w >> 1) * 64; const int wn = (w & 1) * ((JT) * 16); \
  const int lm = l & 15; const int q = l >> 4;

// ---------- kernels ----------

// LN1: x -> bf16 normalized (n1 params)
__global__ __launch_bounds__(256) void k_ln1(const float* __restrict__ x,
                                             const float* __restrict__ g,
                                             const float* __restrict__ b,
                                             unsigned short* __restrict__ o) {
  __shared__ float sred[4];
  int row = blockIdx.x, t = threadIdx.x;
  f32x4 v = ((const f32x4*)(x + (size_t)row * Dn))[t];
  float m = block_sum(v.x + v.y + v.z + v.w, sred, t) * (1.f / Dn);
  f32x4 d = v - m;
  float var = block_sum(d.x * d.x + d.y * d.y + d.z * d.z + d.w * d.w, sred, t) * (1.f / Dn);
  float rs = rsqrtf(var + 1e-5f);
  f32x4 gg = ((const f32x4*)g)[t], bb = ((const f32x4*)b)[t];
  u16x4 r;
  r.x = f2bf(d.x * rs * gg.x + bb.x);
  r.y = f2bf(d.y * rs * gg.y + bb.y);
  r.z = f2bf(d.z * rs * gg.z + bb.z);
  r.w = f2bf(d.w * rs * gg.w + bb.w);
  *((u16x4*)(o + (size_t)row * Dn) + t) = r;
}

// init per-expert fc1 bias accumulators with b1
__global__ __launch_bounds__(256) void k_b1init(const float* __restrict__ ge,
                                                const float* __restrict__ ve,
                                                const float* __restrict__ te,
                                                const float* __restrict__ gen,
                                                float* __restrict__ b1p) {
  int e = blockIdx.y;
  int f = blockIdx.x * 256 + threadIdx.x;
  const float* src = (e == 0) ? ge : (e == 1) ? ve : (e == 2) ? te : gen + (size_t)(e - 3) * Fn;
  b1p[(size_t)e * Fn + f] = src[f];
}

// transpose+convert: W[K][N] fp32 -> Wt[N][K] bf16, optional row scale g[k],
// optional bias fold: bacc[n] += sum_k lnb[k]*W[k][n] (on RAW W)
__global__ __launch_bounds__(256) void k_transpose(const float* __restrict__ W,
                                                   unsigned short* __restrict__ Wt,
                                                   const float* __restrict__ g,
                                                   const float* __restrict__ lnb,
                                                   float* __restrict__ bacc,
                                                   int K, int N) {
  __shared__ float tile[64][65];
  int n0 = blockIdx.x * 64, k0 = blockIdx.y * 64;
  int t = threadIdx.x, j = t & 63, i0 = t >> 6;
  float bsum = 0.f;
#pragma unroll 4
  for (int ii = 0; ii < 16; ++ii) {
    int i = i0 * 16 + ii;
    float wv = W[(size_t)(k0 + i) * N + n0 + j];
    if (lnb) bsum += lnb[k0 + i] * wv;
    tile[i][j] = g ? wv * g[k0 + i] : wv;
  }
  if (bacc) atomicAdd(&bacc[n0 + j], bsum);
  __syncthreads();
#pragma unroll 4
  for (int ii = 0; ii < 16; ++ii) {
    int i = i0 * 16 + ii;
    Wt[(size_t)(n0 + i) * K + k0 + j] = f2bf(tile[j][i]);
  }
}

// QKV projection: out = xn1 @ W + bias, scattered to [B,H,S,hd] (vmode=0) or [B,H,hd,S] (vmode=1)
__global__ __launch_bounds__(256) void k_gemm_qkv(const unsigned short* __restrict__ A,
                                                  const unsigned short* __restrict__ Bt,
                                                  const float* __restrict__ bias,
                                                  unsigned short* __restrict__ out, int vmode) {
  GEMM_PROLOG(4)
  int m0 = blockIdx.y * 128, n0 = blockIdx.x * 128;
  gemm_core<4>(A, Bt, Dn, m0, n0, lA, lB, acc);
  EPI_VARS(4)
#pragma unroll
  for (int i = 0; i < 4; ++i)
#pragma unroll
    for (int j = 0; j < 4; ++j)
#pragma unroll
      for (int r = 0; r < 4; ++r) {
        int row = m0 + wm + i * 16 + q * 4 + r;
        int col = n0 + wn + j * 16 + lm;
        float val = acc[i][j][r] + bias[col];
        int b = row >> 10, s = row & 1023, h = col >> 6, d = col & 63;
        size_t idx = vmode ? (((size_t)((b * Hn + h) * HDn + d)) << 10) + s
                           : ((size_t)((b * Hn + h) << 10) + s) * HDn + d;
        out[idx] = f2bf(val);
      }
}

// scores = q @ k^T * 1/8 -> att bf16 [H][S][S] (per batch)
__global__ __launch_bounds__(256) void k_scores(const unsigned short* __restrict__ qb,
                                                const unsigned short* __restrict__ kb,
                                                unsigned short* __restrict__ att) {
  GEMM_PROLOG(4)
  int h = blockIdx.z;
  const unsigned short* A = qb + (size_t)h * Sn * HDn;
  const unsigned short* Bt = kb + (size_t)h * Sn * HDn;
  int m0 = blockIdx.y * 128, n0 = blockIdx.x * 128;
  gemm_core<4>(A, Bt, HDn, m0, n0, lA, lB, acc);
  EPI_VARS(4)
#pragma unroll
  for (int i = 0; i < 4; ++i)
#pragma unroll
    for (int j = 0; j < 4; ++j)
#pragma unroll
      for (int r = 0; r < 4; ++r) {
        int row = m0 + wm + i * 16 + q * 4 + r;
        int col = n0 + wn + j * 16 + lm;
        att[((size_t)h << 20) + ((size_t)row << 10) + col] = f2bf(acc[i][j][r] * 0.125f);
      }
}

// softmax over last dim of att row (in place, bf16)
__global__ __launch_bounds__(256) void k_softmax(unsigned short* __restrict__ att) {
  __shared__ float sred[4];
  int t = threadIdx.x;
  size_t base = ((size_t)blockIdx.y << 20) + ((size_t)blockIdx.x << 10);
  u16x4 raw = *((u16x4*)(att + base) + t);
  float v0 = bf2f(raw.x), v1 = bf2f(raw.y), v2 = bf2f(raw.z), v3 = bf2f(raw.w);
  float mx = block_max(fmaxf(fmaxf(v0, v1), fmaxf(v2, v3)), sred, t);
  float e0 = expf(v0 - mx), e1 = expf(v1 - mx), e2 = expf(v2 - mx), e3 = expf(v3 - mx);
  float ssum = block_sum(e0 + e1 + e2 + e3, sred, t);
  float inv = 1.f / ssum;
  u16x4 r;
  r.x = f2bf(e0 * inv); r.y = f2bf(e1 * inv); r.z = f2bf(e2 * inv); r.w = f2bf(e3 * inv);
  *((u16x4*)(att + base) + t) = r;
}

// mean over heads -> d_out mean_att region (per batch)
__global__ __launch_bounds__(256) void k_meanatt(const unsigned short* __restrict__ att,
                                                 float* __restrict__ outm) {
  int idx = blockIdx.x * 256 + threadIdx.x;   // 0 .. S*S-1
  float s = 0.f;
#pragma unroll
  for (int h = 0; h < Hn; ++h) s += bf2f(att[((size_t)h << 20) + idx]);
  outm[idx] = s * (1.f / Hn);
}

// o = att @ V  (per batch, per head): A = att[h] [S][S], Bt = v[h] [hd][S]
__global__ __launch_bounds__(256) void k_av(const unsigned short* __restrict__ att,
                                            const unsigned short* __restrict__ vb,
                                            unsigned short* __restrict__ o, int b) {
  GEMM_PROLOG(2)
  int h = blockIdx.z;
  const unsigned short* A = att + ((size_t)h << 20);
  const unsigned short* Bt = vb + (size_t)h * HDn * Sn;
  int m0 = blockIdx.y * 128;
  gemm_core<2>(A, Bt, Sn, m0, 0, lA, lB, acc);
  EPI_VARS(2)
#pragma unroll
  for (int i = 0; i < 4; ++i)
#pragma unroll
    for (int j = 0; j < 2; ++j)
#pragma unroll
      for (int r = 0; r < 4; ++r) {
        int row = m0 + wm + i * 16 + q * 4 + r;       // s
        int col = wn + j * 16 + lm;                   // d in [0,64)
        o[((size_t)((b << 10) + row)) * Dn + h * HDn + col] = f2bf(acc[i][j][r]);
      }
}

// x1 = x + o @ Wo + bo ; also initializes d_out "out" region with x1
__global__ __launch_bounds__(256) void k_ao(const unsigned short* __restrict__ A,
                                            const unsigned short* __restrict__ Bt,
                                            const float* __restrict__ bo,
                                            const float* __restrict__ x,
                                            float* __restrict__ x1,
                                            float* __restrict__ outp) {
  GEMM_PROLOG(4)
  int m0 = blockIdx.y * 128, n0 = blockIdx.x * 128;
  gemm_core<4>(A, Bt, Dn, m0, n0, lA, lB, acc);
  EPI_VARS(4)
#pragma unroll
  for (int i = 0; i < 4; ++i)
#pragma unroll
    for (int j = 0; j < 4; ++j)
#pragma unroll
      for (int r = 0; r < 4; ++r) {
        int row = m0 + wm + i * 16 + q * 4 + r;
        int col = n0 + wn + j * 16 + lm;
        size_t idx = (size_t)row * Dn + col;
        float val = acc[i][j][r] + bo[col] + x[idx];
        x1[idx] = val;
        outp[idx] = val;
      }
}

// LN2 + inner-expert normalize + router (logits/probs/top2 comb), per token row
__global__ __launch_bounds__(256) void k_ln2(const float* __restrict__ x1,
                                             const float* __restrict__ g,
                                             const float* __restrict__ b,
                                             const float* __restrict__ Wr,
                                             const float* __restrict__ br,
                                             unsigned short* __restrict__ ubuf,
                                             float* __restrict__ comb,
                                             float* __restrict__ logits_out,
                                             float* __restrict__ probs_out) {
  __shared__ float sred[4];
  __shared__ float lred[4][En];
  int row = blockIdx.x, t = threadIdx.x;
  f32x4 v = ((const f32x4*)(x1 + (size_t)row * Dn))[t];
  float m1 = block_sum(v.x + v.y + v.z + v.w, sred, t) * (1.f / Dn);
  f32x4 d = v - m1;
  float var1 = block_sum(d.x * d.x + d.y * d.y + d.z * d.z + d.w * d.w, sred, t) * (1.f / Dn);
  float rs1 = rsqrtf(var1 + 1e-5f);
  f32x4 gg = ((const f32x4*)g)[t], bb = ((const f32x4*)b)[t];
  f32x4 xn = d * rs1 * gg + bb;                  // xn2 (router input)
  float m2 = block_sum(xn.x + xn.y + xn.z + xn.w, sred, t) * (1.f / Dn);
  f32x4 d2 = xn - m2;
  float var2 = block_sum(d2.x * d2.x + d2.y * d2.y + d2.z * d2.z + d2.w * d2.w, sred, t) * (1.f / Dn);
  float rs2 = rsqrtf(var2 + 1e-5f);
  u16x4 r;
  r.x = f2bf(d2.x * rs2); r.y = f2bf(d2.y * rs2);
  r.z = f2bf(d2.z * rs2); r.w = f2bf(d2.w * rs2);
  *((u16x4*)(ubuf + (size_t)row * Dn) + t) = r;
  // router logits
  float lacc[En];
#pragma unroll
  for (int e = 0; e < En; ++e) lacc[e] = 0.f;
  int d0 = t * 4;
#pragma unroll
  for (int c = 0; c < 4; ++c) {
    const float* wr = Wr + (size_t)(d0 + c) * En;
    float xv = xn[c];
#pragma unroll
    for (int e = 0; e < En; ++e) lacc[e] += xv * wr[e];
  }
#pragma unroll
  for (int e = 0; e < En; ++e) lacc[e] = wsum(lacc[e]);
  __syncthreads();
  if ((t & 63) == 0)
#pragma unroll
    for (int e = 0; e < En; ++e) lred[t >> 6][e] = lacc[e];
  __syncthreads();
  if (t == 0) {
    float lg[En];
#pragma unroll
    for (int e = 0; e < En; ++e)
      lg[e] = lred[0][e] + lred[1][e] + lred[2][e] + lred[3][e] + br[e];
    for (int e = 0; e < En; ++e) logits_out[(size_t)row * En + e] = lg[e];
    float mx = lg[0];
    for (int e = 1; e < En; ++e) mx = fmaxf(mx, lg[e]);
    float pe[En], ssum = 0.f;
    for (int e = 0; e < En; ++e) { pe[e] = expf(lg[e] - mx); ssum += pe[e]; }
    float inv = 1.f / ssum;
    float pr[En];
    for (int e = 0; e < En; ++e) { pr[e] = pe[e] * inv; probs_out[(size_t)row * En + e] = pr[e]; }
    int i0 = 0;
    for (int e = 1; e < En; ++e) if (pr[e] > pr[i0]) i0 = e;
    int i1 = (i0 == 0) ? 1 : 0;
    for (int e = 0; e < En; ++e) if (e != i0 && pr[e] > pr[i1]) i1 = e;
    float e1 = expf(pr[i1] - pr[i0]);
    float w0 = 1.f / (1.f + e1), w1 = e1 / (1.f + e1);
    for (int e = 0; e < En; ++e) {
      float cv = (e == i0) ? w0 : (e == i1) ? w1 : 0.f;
      comb[(size_t)row * En + e] = cv;
    }
  }
}

// fc1 + exact gelu -> h bf16
__global__ __launch_bounds__(256) void k_gemm1(const unsigned short* __restrict__ A,
                                               const unsigned short* __restrict__ Bt,
                                               const float* __restrict__ b1,
                                               unsigned short* __restrict__ hout) {
  GEMM_PROLOG(4)
  int m0 = blockIdx.y * 128, n0 = blockIdx.x * 128;
  gemm_core<4>(A, Bt, Dn, m0, n0, lA, lB, acc);
  EPI_VARS(4)
#pragma unroll
  for (int i = 0; i < 4; ++i)
#pragma unroll
    for (int j = 0; j < 4; ++j)
#pragma unroll
      for (int r = 0; r < 4; ++r) {
        int row = m0 + wm + i * 16 + q * 4 + r;
        int col = n0 + wn + j * 16 + lm;
        float val = acc[i][j][r] + b1[col];
        val = 0.5f * val * (1.f + erff(val * 0.70710678118654752f));
        hout[(size_t)row * Fn + col] = f2bf(val);
      }
}

// fc2, scaled accumulate into d_out "out" region.
// mode 0: scale 1 (ge); 1: modality==0 (ve); 2: modality==1 (te); 3: comb[:,ccol] (general)
__global__ __launch_bounds__(256) void k_gemm2(const unsigned short* __restrict__ A,
                                               const unsigned short* __restrict__ Bt,
                                               const float* __restrict__ b2,
                                               float* __restrict__ outp, int mode,
                                               const int* __restrict__ modality,
                                               const float* __restrict__ comb, int ccol) {
  GEMM_PROLOG(4)
  int m0 = blockIdx.y * 128, n0 = blockIdx.x * 128;
  gemm_core<4>(A, Bt, Fn, m0, n0, lA, lB, acc);
  EPI_VARS(4)
#pragma unroll
  for (int i = 0; i < 4; ++i)
#pragma unroll
    for (int j = 0; j < 4; ++j)
#pragma unroll
      for (int r = 0; r < 4; ++r) {
        int row = m0 + wm + i * 16 + q * 4 + r;
        int col = n0 + wn + j * 16 + lm;
        float sc;
        if (mode == 0) sc = 1.f;
        else if (mode == 1) sc = (modality[row] == 0) ? 1.f : 0.f;
        else if (mode == 2) sc = (modality[row] == 1) ? 1.f : 0.f;
        else sc = comb[(size_t)row * En + ccol];
        if (sc != 0.f) {
          size_t idx = (size_t)row * Dn + col;
          outp[idx] += sc * (acc[i][j][r] + b2[col]);
        }
      }
}

// ---------- host ----------
extern "C" void kernel_launch(void* const* d_in, const int* in_sizes, int n_in,
                              void* d_out, int out_size, void* d_ws, size_t ws_size,
                              hipStream_t stream) {
  (void)in_sizes; (void)n_in; (void)out_size; (void)ws_size;
  const float* x       = (const float*)d_in[0];
  const int*   modality= (const int*)d_in[1];
  const float* n1g = (const float*)d_in[2];
  const float* n1b = (const float*)d_in[3];
  const float* n2g = (const float*)d_in[4];
  const float* n2b = (const float*)d_in[5];
  const float* Wq = (const float*)d_in[6];  const float* bq = (const float*)d_in[7];
  const float* Wk = (const float*)d_in[8];  const float* bk = (const float*)d_in[9];
  const float* Wv = (const float*)d_in[10]; const float* bv = (const float*)d_in[11];
  const float* Wo = (const float*)d_in[12]; const float* bo = (const float*)d_in[13];
  const float* Wr = (const float*)d_in[14]; const float* br = (const float*)d_in[15];
  const float* gen_lng = (const float*)d_in[16];
  const float* gen_lnb = (const float*)d_in[17];
  const float* gen_W1  = (const float*)d_in[18];
  const float* gen_b1  = (const float*)d_in[19];
  const float* gen_W2  = (const float*)d_in[20];
  const float* gen_b2  = (const float*)d_in[21];
  const float* ge_lng = (const float*)d_in[22]; const float* ge_lnb = (const float*)d_in[23];
  const float* ge_W1  = (const float*)d_in[24]; const float* ge_b1  = (const float*)d_in[25];
  const float* ge_W2  = (const float*)d_in[26]; const float* ge_b2  = (const float*)d_in[27];
  const float* ve_lng = (const float*)d_in[28]; const float* ve_lnb = (const float*)d_in[29];
  const float* ve_W1  = (const float*)d_in[30]; const float* ve_b1  = (const float*)d_in[31];
  const float* ve_W2  = (const float*)d_in[32]; const float* ve_b2  = (const float*)d_in[33];
  const float* te_lng = (const float*)d_in[34]; const float* te_lnb = (const float*)d_in[35];
  const float* te_W1  = (const float*)d_in[36]; const float* te_b1  = (const float*)d_in[37];
  const float* te_W2  = (const float*)d_in[38]; const float* te_b2  = (const float*)d_in[39];

  float* outp = (float*)d_out;

  char* wsp = (char*)d_ws;
  size_t off = 0;
  auto alloc = [&](size_t bytes) -> void* {
    void* p = wsp + off;
    off += (bytes + 255) & ~(size_t)255;
    return p;
  };
  unsigned short* xn1 = (unsigned short*)alloc((size_t)Mn * Dn * 2);          // 8MB
  unsigned short* wqkT= (unsigned short*)alloc((size_t)4 * Dn * Dn * 2);      // 8MB
  unsigned short* qb  = (unsigned short*)alloc((size_t)Bn * Hn * Sn * HDn * 2); // 8MB
  unsigned short* kb  = (unsigned short*)alloc((size_t)Bn * Hn * Sn * HDn * 2); // 8MB
  unsigned short* vb  = (unsigned short*)alloc((size_t)Bn * Hn * HDn * Sn * 2); // 8MB
  unsigned short* attb= (unsigned short*)alloc((size_t)Hn * Sn * Sn * 2);     // 32MB (per-batch)
  unsigned short* ob  = (unsigned short*)alloc((size_t)Mn * Dn * 2);          // 8MB
  float*          x1  = (float*)alloc((size_t)Mn * Dn * 4);                   // 16MB
  unsigned short* ub  = (unsigned short*)alloc((size_t)Mn * Dn * 2);          // 8MB
  float*          comb= (float*)alloc((size_t)Mn * En * 4);                   // 128KB
  float*          b1p = (float*)alloc((size_t)11 * Fn * 4);                   // 176KB
  unsigned short* w1T = (unsigned short*)alloc((size_t)Fn * Dn * 2);          // 8MB
  unsigned short* w2T = (unsigned short*)alloc((size_t)Dn * Fn * 2);          // 8MB
  unsigned short* hb  = (unsigned short*)alloc((size_t)Mn * Fn * 2);          // 32MB

  k_ln1<<<Mn, 256, 0, stream>>>(x, n1g, n1b, xn1);
  k_b1init<<<dim3(Fn / 256, 11), 256, 0, stream>>>(ge_b1, ve_b1, te_b1, gen_b1, b1p);

  const float* wmats[4] = {Wq, Wk, Wv, Wo};
  for (int p = 0; p < 4; ++p)
    k_transpose<<<dim3(Dn / 64, Dn / 64), 256, 0, stream>>>(
        wmats[p], wqkT + (size_t)p * Dn * Dn, nullptr, nullptr, nullptr, Dn, Dn);

  k_gemm_qkv<<<dim3(8, 32), 256, 0, stream>>>(xn1, wqkT,                      bq, qb, 0);
  k_gemm_qkv<<<dim3(8, 32), 256, 0, stream>>>(xn1, wqkT + (size_t)1 * Dn * Dn, bk, kb, 0);
  k_gemm_qkv<<<dim3(8, 32), 256, 0, stream>>>(xn1, wqkT + (size_t)2 * Dn * Dn, bv, vb, 1);

  for (int b = 0; b < Bn; ++b) {
    const unsigned short* qbb = qb + (size_t)b * Hn * Sn * HDn;
    const unsigned short* kbb = kb + (size_t)b * Hn * Sn * HDn;
    const unsigned short* vbb = vb + (size_t)b * Hn * HDn * Sn;
    k_scores<<<dim3(8, 8, Hn), 256, 0, stream>>>(qbb, kbb, attb);
    k_softmax<<<dim3(Sn, Hn), 256, 0, stream>>>(attb);
    k_meanatt<<<Sn * Sn / 256, 256, 0, stream>>>(attb, outp + MEANOFF + (size_t)b * Sn * Sn);
    k_av<<<dim3(1, 8, Hn), 256, 0, stream>>>(attb, vbb, ob, b);
  }

  k_ao<<<dim3(8, 32), 256, 0, stream>>>(ob, wqkT + (size_t)3 * Dn * Dn, bo, x, x1, outp);
  k_ln2<<<Mn, 256, 0, stream>>>(x1, n2g, n2b, Wr, br, ub, comb, outp + LOGOFF, outp + PROBOFF);

  for (int e = 0; e < 11; ++e) {
    const float *W1, *W2, *b2v, *lng, *lnb;
    int mode, ccol = 0;
    if (e == 0)      { W1 = ge_W1; W2 = ge_W2; b2v = ge_b2; lng = ge_lng; lnb = ge_lnb; mode = 0; }
    else if (e == 1) { W1 = ve_W1; W2 = ve_W2; b2v = ve_b2; lng = ve_lng; lnb = ve_lnb; mode = 1; }
    else if (e == 2) { W1 = te_W1; W2 = te_W2; b2v = te_b2; lng = te_lng; lnb = te_lnb; mode = 2; }
    else {
      int gi = e - 3;
      W1 = gen_W1 + (size_t)gi * Dn * Fn; W2 = gen_W2 + (size_t)gi * Fn * Dn;
      b2v = gen_b2 + (size_t)gi * Dn; lng = gen_lng + (size_t)gi * Dn; lnb = gen_lnb + (size_t)gi * Dn;
      mode = 3; ccol = gi;
    }
    k_transpose<<<dim3(Fn / 64, Dn / 64), 256, 0, stream>>>(W1, w1T, lng, lnb, b1p + (size_t)e * Fn, Dn, Fn);
    k_transpose<<<dim3(Dn / 64, Fn / 64), 256, 0, stream>>>(W2, w2T, nullptr, nullptr, nullptr, Fn, Dn);
    k_gemm1<<<dim3(32, 32), 256, 0, stream>>>(ub, w1T, b1p + (size_t)e * Fn, hb);
    k_gemm2<<<dim3(8, 32), 256, 0, stream>>>(hb, w2T, b2v, outp, mode, modality, comb, ccol);
  }
}

// Round 2
// 2215.262 us; speedup vs baseline: 1.2401x; 1.2401x over previous
//
#include <hip/hip_runtime.h>
#include <stdint.h>

// ---------- constants ----------
#define Bn 4
#define Sn 1024
#define Dn 1024
#define Fn 4096
#define En 8
#define Hn 16
#define HDn 64
#define Mn 4096           // B*S tokens
#define LOGOFF 4194304    // B*S*D
#define PROBOFF 4227072   // + B*S*E
#define MEANOFF 4259840   // + B*S*E

typedef __attribute__((ext_vector_type(8))) short short8;
typedef __attribute__((ext_vector_type(4))) float f32x4;
typedef __attribute__((ext_vector_type(4))) unsigned short u16x4;

#define DEV static __device__ __forceinline__

struct P8 { const float* p[8]; };

DEV float bf2f(unsigned short u) {
  union { uint32_t i; float f; } x; x.i = ((uint32_t)u) << 16; return x.f;
}
DEV unsigned short f2bf(float f) {
  union { float f; uint32_t i; } x; x.f = f;
  uint32_t r = x.i + 0x7FFFu + ((x.i >> 16) & 1u);
  return (unsigned short)(r >> 16);
}

DEV void gl_lds16(const void* g, void* l) {
  __builtin_amdgcn_global_load_lds((const __attribute__((address_space(1))) void*)g,
                                   (__attribute__((address_space(3))) void*)l,
                                   16, 0, 0);
}

DEV float wsum(float v) { for (int o = 1; o < 64; o <<= 1) v += __shfl_xor(v, o); return v; }
DEV float wmaxr(float v) { for (int o = 1; o < 64; o <<= 1) v = fmaxf(v, __shfl_xor(v, o)); return v; }

DEV float block_sum(float v, float* sred, int t) {
  int w = t >> 6, l = t & 63;
  v = wsum(v);
  __syncthreads();
  if (l == 0) sred[w] = v;
  __syncthreads();
  return sred[0] + sred[1] + sred[2] + sred[3];
}
DEV float block_max(float v, float* sred, int t) {
  int w = t >> 6, l = t & 63;
  v = wmaxr(v);
  __syncthreads();
  if (l == 0) sred[w] = v;
  __syncthreads();
  return fmaxf(fmaxf(sred[0], sred[1]), fmaxf(sred[2], sred[3]));
}

// ---------- GEMM core with precomputed per-lane row pointers ----------
// A rows (2 per lane for 128-tile) and Bt rows, all advanced 32 bf16/iter.
template<int JT>
DEV void gemm_core_p(const unsigned short* a0, const unsigned short* a1,
                     const unsigned short* b0, const unsigned short* b1,
                     int kiters, unsigned short* lA, unsigned short* lB, f32x4 (&acc)[4][JT]) {
  const int t = threadIdx.x, w = t >> 6, l = t & 63;
  const int wm = (w >> 1) * 64, wn = (w & 1) * (JT * 16);
  const int lm = l & 15, q = l >> 4;
  for (int it = 0; it < kiters; ++it) {
    gl_lds16(a0, lA + w * 1024);
    gl_lds16(a1, lA + w * 1024 + 512);
    if (JT == 4) {
      gl_lds16(b0, lB + w * 1024);
      gl_lds16(b1, lB + w * 1024 + 512);
      b1 += 32;
    } else {
      gl_lds16(b0, lB + w * 512);
    }
    a0 += 32; a1 += 32; b0 += 32;
    __syncthreads();
    short8 af[4], bfr[JT];
#pragma unroll
    for (int i = 0; i < 4; ++i) af[i] = *(const short8*)(lA + (wm + i * 16 + lm) * 32 + q * 8);
#pragma unroll
    for (int j = 0; j < JT; ++j) bfr[j] = *(const short8*)(lB + (wn + j * 16 + lm) * 32 + q * 8);
#pragma unroll
    for (int i = 0; i < 4; ++i)
#pragma unroll
      for (int j = 0; j < JT; ++j)
        acc[i][j] = __builtin_amdgcn_mfma_f32_16x16x32_bf16(af[i], bfr[j], acc[i][j], 0, 0, 0);
    __syncthreads();
  }
}

#define GEMM_PROLOG(JT)                                         \
  __shared__ __align__(16) unsigned short lA[128 * 32];         \
  __shared__ __align__(16) unsigned short lB[(JT) * 32 * 32];   \
  f32x4 acc[4][JT];                                             \
  _Pragma("unroll") for (int i = 0; i < 4; ++i)                 \
  _Pragma("unroll") for (int j = 0; j < (JT); ++j)              \
      acc[i][j] = (f32x4){0.f, 0.f, 0.f, 0.f};

#define GVARS(JT)                                               \
  const int t = threadIdx.x, w = t >> 6, l = t & 63;            \
  const int lr = l >> 2, lko = (l & 3) * 8;                     \
  const int wm = (w >> 1) * 64, wn = (w & 1) * ((JT) * 16);     \
  const int lm = l & 15, q = l >> 4;                            \
  (void)lr; (void)lko; (void)wm; (void)wn; (void)lm; (void)q;

// ---------- small kernels ----------

__global__ __launch_bounds__(64) void k_init(int* __restrict__ cnt) {
  if (threadIdx.x < 16) cnt[threadIdx.x] = 0;
}

__global__ __launch_bounds__(64) void k_finalize(const int* __restrict__ cnt,
                                                 int* __restrict__ offA,
                                                 int* __restrict__ hbase) {
  if (threadIdx.x == 0) {
    const int* cg = cnt;        // 8 general
    const int* cm = cnt + 8;    // 2 modality
    offA[0] = 0; offA[1] = Mn; offA[2] = Mn + cm[0];
    int h = 0;
    for (int e = 0; e < 4; ++e) { hbase[e] = h; h += cg[e]; }
    h = 0;
    for (int e = 4; e < 8; ++e) { hbase[e] = h; h += cg[e]; }
  }
}

// LN1: x -> bf16 normalized (n1 params)
__global__ __launch_bounds__(256) void k_ln1(const float* __restrict__ x,
                                             const float* __restrict__ g,
                                             const float* __restrict__ b,
                                             unsigned short* __restrict__ o) {
  __shared__ float sred[4];
  int row = blockIdx.x, t = threadIdx.x;
  f32x4 v = ((const f32x4*)(x + (size_t)row * Dn))[t];
  float m = block_sum(v.x + v.y + v.z + v.w, sred, t) * (1.f / Dn);
  f32x4 d = v - m;
  float var = block_sum(d.x * d.x + d.y * d.y + d.z * d.z + d.w * d.w, sred, t) * (1.f / Dn);
  float rs = rsqrtf(var + 1e-5f);
  f32x4 gg = ((const f32x4*)g)[t], bb = ((const f32x4*)b)[t];
  u16x4 r;
  r.x = f2bf(d.x * rs * gg.x + bb.x);
  r.y = f2bf(d.y * rs * gg.y + bb.y);
  r.z = f2bf(d.z * rs * gg.z + bb.z);
  r.w = f2bf(d.w * rs * gg.w + bb.w);
  *((u16x4*)(o + (size_t)row * Dn) + t) = r;
}

// init per-expert fc1 bias accumulators with b1
__global__ __launch_bounds__(256) void k_b1init(const float* __restrict__ ge,
                                                const float* __restrict__ ve,
                                                const float* __restrict__ te,
                                                const float* __restrict__ gen,
                                                float* __restrict__ b1p) {
  int e = blockIdx.y;
  int f = blockIdx.x * 256 + threadIdx.x;
  const float* src = (e == 0) ? ge : (e == 1) ? ve : (e == 2) ? te : gen + (size_t)(e - 3) * Fn;
  b1p[(size_t)e * Fn + f] = src[f];
}

// batched transpose+convert: W[K][N] fp32 -> Wt[N][K] bf16 (z-th mat)
// useGL: fold row scale g[k] into Wt and bacc[n] += sum_k lnb[k]*W_raw[k][n]
__global__ __launch_bounds__(256) void k_transpose(P8 Ws, P8 Gs, P8 Ls, int useGL,
                                                   float* __restrict__ b1p, int b1base,
                                                   unsigned short* __restrict__ Wt, size_t dstStride,
                                                   int K, int N) {
  __shared__ float tile[64][65];
  int z = blockIdx.z;
  const float* W = Ws.p[z];
  int n0 = blockIdx.x * 64, k0 = blockIdx.y * 64;
  int t = threadIdx.x, j = t & 63, i0 = t >> 6;
  const float* g = useGL ? Gs.p[z] : nullptr;
  const float* lnb = useGL ? Ls.p[z] : nullptr;
  float bsum = 0.f;
#pragma unroll 4
  for (int ii = 0; ii < 16; ++ii) {
    int i = i0 * 16 + ii;
    float wv = W[(size_t)(k0 + i) * N + n0 + j];
    if (useGL) { bsum += lnb[k0 + i] * wv; wv *= g[k0 + i]; }
    tile[i][j] = wv;
  }
  if (useGL) atomicAdd(&b1p[(size_t)(b1base + z) * Fn + n0 + j], bsum);
  __syncthreads();
  unsigned short* dst = Wt + (size_t)z * dstStride;
#pragma unroll 4
  for (int ii = 0; ii < 16; ++ii) {
    int i = i0 * 16 + ii;
    dst[(size_t)(n0 + i) * K + k0 + j] = f2bf(tile[j][i]);
  }
}

// QKV projection: out = xn1 @ W + bias, scattered to [B,H,S,hd] (vmode=0) or [B,H,hd,S] (vmode=1)
__global__ __launch_bounds__(256) void k_gemm_qkv(const unsigned short* __restrict__ A,
                                                  const unsigned short* __restrict__ Bt,
                                                  const float* __restrict__ bias,
                                                  unsigned short* __restrict__ out, int vmode) {
  GEMM_PROLOG(4) GVARS(4)
  int m0 = blockIdx.y * 128, n0 = blockIdx.x * 128;
  const unsigned short* a0 = A + (size_t)(m0 + w * 32 + lr) * Dn + lko;
  const unsigned short* b0 = Bt + (size_t)(n0 + w * 32 + lr) * Dn + lko;
  gemm_core_p<4>(a0, a0 + 16 * Dn, b0, b0 + 16 * Dn, Dn / 32, lA, lB, acc);
#pragma unroll
  for (int i = 0; i < 4; ++i)
#pragma unroll
    for (int j = 0; j < 4; ++j)
#pragma unroll
      for (int r = 0; r < 4; ++r) {
        int row = m0 + wm + i * 16 + q * 4 + r;
        int col = n0 + wn + j * 16 + lm;
        float val = acc[i][j][r] + bias[col];
        int b = row >> 10, s = row & 1023, h = col >> 6, d = col & 63;
        size_t idx = vmode ? (((size_t)((b * Hn + h) * HDn + d)) << 10) + s
                           : ((size_t)((b * Hn + h) << 10) + s) * HDn + d;
        out[idx] = f2bf(val);
      }
}

// scores = q @ k^T * 1/8 -> att bf16 [H][S][S] (per batch)
__global__ __launch_bounds__(256) void k_scores(const unsigned short* __restrict__ qb,
                                                const unsigned short* __restrict__ kb,
                                                unsigned short* __restrict__ att) {
  GEMM_PROLOG(4) GVARS(4)
  int h = blockIdx.z;
  const unsigned short* A = qb + (size_t)h * Sn * HDn;
  const unsigned short* Bt = kb + (size_t)h * Sn * HDn;
  int m0 = blockIdx.y * 128, n0 = blockIdx.x * 128;
  const unsigned short* a0 = A + (size_t)(m0 + w * 32 + lr) * HDn + lko;
  const unsigned short* b0 = Bt + (size_t)(n0 + w * 32 + lr) * HDn + lko;
  gemm_core_p<4>(a0, a0 + 16 * HDn, b0, b0 + 16 * HDn, HDn / 32, lA, lB, acc);
#pragma unroll
  for (int i = 0; i < 4; ++i)
#pragma unroll
    for (int j = 0; j < 4; ++j)
#pragma unroll
      for (int r = 0; r < 4; ++r) {
        int row = m0 + wm + i * 16 + q * 4 + r;
        int col = n0 + wn + j * 16 + lm;
        att[((size_t)h << 20) + ((size_t)row << 10) + col] = f2bf(acc[i][j][r] * 0.125f);
      }
}

// softmax over last dim of att row (in place, bf16)
__global__ __launch_bounds__(256) void k_softmax(unsigned short* __restrict__ att) {
  __shared__ float sred[4];
  int t = threadIdx.x;
  size_t base = ((size_t)blockIdx.y << 20) + ((size_t)blockIdx.x << 10);
  u16x4 raw = *((u16x4*)(att + base) + t);
  float v0 = bf2f(raw.x), v1 = bf2f(raw.y), v2 = bf2f(raw.z), v3 = bf2f(raw.w);
  float mx = block_max(fmaxf(fmaxf(v0, v1), fmaxf(v2, v3)), sred, t);
  float e0 = expf(v0 - mx), e1 = expf(v1 - mx), e2 = expf(v2 - mx), e3 = expf(v3 - mx);
  float ssum = block_sum(e0 + e1 + e2 + e3, sred, t);
  float inv = 1.f / ssum;
  u16x4 r;
  r.x = f2bf(e0 * inv); r.y = f2bf(e1 * inv); r.z = f2bf(e2 * inv); r.w = f2bf(e3 * inv);
  *((u16x4*)(att + base) + t) = r;
}

// mean over heads -> d_out mean_att region (per batch)
__global__ __launch_bounds__(256) void k_meanatt(const unsigned short* __restrict__ att,
                                                 float* __restrict__ outm) {
  int idx = blockIdx.x * 256 + threadIdx.x;
  float s = 0.f;
#pragma unroll
  for (int h = 0; h < Hn; ++h) s += bf2f(att[((size_t)h << 20) + idx]);
  outm[idx] = s * (1.f / Hn);
}

// o = att @ V  (per batch, per head)
__global__ __launch_bounds__(256) void k_av(const unsigned short* __restrict__ att,
                                            const unsigned short* __restrict__ vb,
                                            unsigned short* __restrict__ o, int b) {
  GEMM_PROLOG(2) GVARS(2)
  int h = blockIdx.z;
  const unsigned short* A = att + ((size_t)h << 20);
  const unsigned short* Bt = vb + (size_t)h * HDn * Sn;
  int m0 = blockIdx.y * 128;
  const unsigned short* a0 = A + (size_t)(m0 + w * 32 + lr) * Sn + lko;
  const unsigned short* b0 = Bt + (size_t)(w * 16 + lr) * Sn + lko;
  gemm_core_p<2>(a0, a0 + 16 * Sn, b0, b0, Sn / 32, lA, lB, acc);
#pragma unroll
  for (int i = 0; i < 4; ++i)
#pragma unroll
    for (int j = 0; j < 2; ++j)
#pragma unroll
      for (int r = 0; r < 4; ++r) {
        int row = m0 + wm + i * 16 + q * 4 + r;
        int col = wn + j * 16 + lm;
        o[((size_t)((b << 10) + row)) * Dn + h * HDn + col] = f2bf(acc[i][j][r]);
      }
}

// x1 = x + o @ Wo + bo ; also initializes d_out "out" region with x1
__global__ __launch_bounds__(256) void k_ao(const unsigned short* __restrict__ A,
                                            const unsigned short* __restrict__ Bt,
                                            const float* __restrict__ bo,
                                            const float* __restrict__ x,
                                            float* __restrict__ x1,
                                            float* __restrict__ outp) {
  GEMM_PROLOG(4) GVARS(4)
  int m0 = blockIdx.y * 128, n0 = blockIdx.x * 128;
  const unsigned short* a0 = A + (size_t)(m0 + w * 32 + lr) * Dn + lko;
  const unsigned short* b0 = Bt + (size_t)(n0 + w * 32 + lr) * Dn + lko;
  gemm_core_p<4>(a0, a0 + 16 * Dn, b0, b0 + 16 * Dn, Dn / 32, lA, lB, acc);
#pragma unroll
  for (int i = 0; i < 4; ++i)
#pragma unroll
    for (int j = 0; j < 4; ++j)
#pragma unroll
      for (int r = 0; r < 4; ++r) {
        int row = m0 + wm + i * 16 + q * 4 + r;
        int col = n0 + wn + j * 16 + lm;
        size_t idx = (size_t)row * Dn + col;
        float val = acc[i][j][r] + bo[col] + x[idx];
        x1[idx] = val;
        outp[idx] = val;
      }
}

// LN2 + inner-expert normalize + router + routing lists
__global__ __launch_bounds__(256) void k_ln2(const float* __restrict__ x1,
                                             const float* __restrict__ g,
                                             const float* __restrict__ b,
                                             const float* __restrict__ Wr,
                                             const float* __restrict__ br,
                                             unsigned short* __restrict__ ubuf,
                                             float* __restrict__ logits_out,
                                             float* __restrict__ probs_out,
                                             int* __restrict__ cnt,            // [0..7] gen, [8..9] modality
                                             int* __restrict__ idx_g,
                                             float* __restrict__ wt_g,
                                             int* __restrict__ idx_m,
                                             const int* __restrict__ modality) {
  __shared__ float sred[4];
  __shared__ float lred[4][En];
  int row = blockIdx.x, t = threadIdx.x;
  f32x4 v = ((const f32x4*)(x1 + (size_t)row * Dn))[t];
  float m1 = block_sum(v.x + v.y + v.z + v.w, sred, t) * (1.f / Dn);
  f32x4 d = v - m1;
  float var1 = block_sum(d.x * d.x + d.y * d.y + d.z * d.z + d.w * d.w, sred, t) * (1.f / Dn);
  float rs1 = rsqrtf(var1 + 1e-5f);
  f32x4 gg = ((const f32x4*)g)[t], bb = ((const f32x4*)b)[t];
  f32x4 xn = d * rs1 * gg + bb;
  float m2 = block_sum(xn.x + xn.y + xn.z + xn.w, sred, t) * (1.f / Dn);
  f32x4 d2 = xn - m2;
  float var2 = block_sum(d2.x * d2.x + d2.y * d2.y + d2.z * d2.z + d2.w * d2.w, sred, t) * (1.f / Dn);
  float rs2 = rsqrtf(var2 + 1e-5f);
  u16x4 r;
  r.x = f2bf(d2.x * rs2); r.y = f2bf(d2.y * rs2);
  r.z = f2bf(d2.z * rs2); r.w = f2bf(d2.w * rs2);
  *((u16x4*)(ubuf + (size_t)row * Dn) + t) = r;
  // router logits
  float lacc[En];
#pragma unroll
  for (int e = 0; e < En; ++e) lacc[e] = 0.f;
  int d0 = t * 4;
#pragma unroll
  for (int c = 0; c < 4; ++c) {
    const float* wr = Wr + (size_t)(d0 + c) * En;
    float xv = xn[c];
#pragma unroll
    for (int e = 0; e < En; ++e) lacc[e] += xv * wr[e];
  }
#pragma unroll
  for (int e = 0; e < En; ++e) lacc[e] = wsum(lacc[e]);
  __syncthreads();
  if ((t & 63) == 0)
#pragma unroll
    for (int e = 0; e < En; ++e) lred[t >> 6][e] = lacc[e];
  __syncthreads();
  if (t == 0) {
    float lg[En];
#pragma unroll
    for (int e = 0; e < En; ++e)
      lg[e] = lred[0][e] + lred[1][e] + lred[2][e] + lred[3][e] + br[e];
    for (int e = 0; e < En; ++e) logits_out[(size_t)row * En + e] = lg[e];
    float mx = lg[0];
    for (int e = 1; e < En; ++e) mx = fmaxf(mx, lg[e]);
    float pe[En], ssum = 0.f;
    for (int e = 0; e < En; ++e) { pe[e] = expf(lg[e] - mx); ssum += pe[e]; }
    float inv = 1.f / ssum;
    float pr[En];
    for (int e = 0; e < En; ++e) { pr[e] = pe[e] * inv; probs_out[(size_t)row * En + e] = pr[e]; }
    int i0 = 0;
    for (int e = 1; e < En; ++e) if (pr[e] > pr[i0]) i0 = e;
    int i1 = (i0 == 0) ? 1 : 0;
    for (int e = 0; e < En; ++e) if (e != i0 && pr[e] > pr[i1]) i1 = e;
    float ee = expf(pr[i1] - pr[i0]);
    float w0 = 1.f / (1.f + ee), w1 = ee / (1.f + ee);
    int p0 = atomicAdd(&cnt[i0], 1);
    idx_g[i0 * Mn + p0] = row; wt_g[i0 * Mn + p0] = w0;
    int p1 = atomicAdd(&cnt[i1], 1);
    idx_g[i1 * Mn + p1] = row; wt_g[i1 * Mn + p1] = w1;
    int md = modality[row];
    int pm = atomicAdd(&cnt[8 + md], 1);
    idx_m[md * Mn + pm] = row;
  }
}

// ---- pass A: z=0 dense ge, z=1 ve (modality 0 list), z=2 te (modality 1 list) ----
__global__ __launch_bounds__(256) void k_fc1A(const unsigned short* __restrict__ ub,
                                              const unsigned short* __restrict__ w1T3,
                                              const float* __restrict__ b1p,
                                              const int* __restrict__ cnt,
                                              const int* __restrict__ idx_m,
                                              const int* __restrict__ offA,
                                              unsigned short* __restrict__ hb) {
  int z = blockIdx.z;
  int flat = blockIdx.x;
  int mt = flat & 31, nt = flat >> 5;
  int rows = (z == 0) ? Mn : cnt[8 + z - 1];
  int m0 = mt * 128;
  if (m0 >= rows) return;
  GEMM_PROLOG(4) GVARS(4)
  int r0 = m0 + w * 32 + lr, r1 = r0 + 16;
  int c0 = (r0 < rows) ? r0 : rows - 1;
  int c1 = (r1 < rows) ? r1 : rows - 1;
  int g0 = (z == 0) ? c0 : idx_m[(z - 1) * Mn + c0];
  int g1 = (z == 0) ? c1 : idx_m[(z - 1) * Mn + c1];
  const unsigned short* a0 = ub + (size_t)g0 * Dn + lko;
  const unsigned short* a1 = ub + (size_t)g1 * Dn + lko;
  const unsigned short* Bt = w1T3 + (size_t)z * Fn * Dn;
  int n0 = nt * 128;
  const unsigned short* b0 = Bt + (size_t)(n0 + w * 32 + lr) * Dn + lko;
  gemm_core_p<4>(a0, a1, b0, b0 + 16 * Dn, Dn / 32, lA, lB, acc);
  const float* bias = b1p + (size_t)z * Fn;
  int hbase = offA[z];
#pragma unroll
  for (int i = 0; i < 4; ++i)
#pragma unroll
    for (int j = 0; j < 4; ++j)
#pragma unroll
      for (int r = 0; r < 4; ++r) {
        int row = m0 + wm + i * 16 + q * 4 + r;
        if (row < rows) {
          int col = n0 + wn + j * 16 + lm;
          float val = acc[i][j][r] + bias[col];
          val = 0.5f * val * (1.f + erff(val * 0.70710678118654752f));
          hb[(size_t)(hbase + row) * Fn + col] = f2bf(val);
        }
      }
}

__global__ __launch_bounds__(256) void k_fc2A(const unsigned short* __restrict__ hb,
                                              const unsigned short* __restrict__ w2T3,
                                              const float* __restrict__ b2a,
                                              const float* __restrict__ b2b,
                                              const float* __restrict__ b2c,
                                              const int* __restrict__ cnt,
                                              const int* __restrict__ idx_m,
                                              const int* __restrict__ offA,
                                              float* __restrict__ outp) {
  int z = blockIdx.z;
  int flat = blockIdx.x;        // 0..255: mt fastest for XCD A-reuse
  int mt = flat & 31, nt = flat >> 5;
  int rows = (z == 0) ? Mn : cnt[8 + z - 1];
  int m0 = mt * 128;
  if (m0 >= rows) return;
  GEMM_PROLOG(4) GVARS(4)
  int hbase = offA[z];
  int r0 = m0 + w * 32 + lr, r1 = r0 + 16;
  int c0 = (r0 < rows) ? r0 : rows - 1;
  int c1 = (r1 < rows) ? r1 : rows - 1;
  const unsigned short* a0 = hb + (size_t)(hbase + c0) * Fn + lko;
  const unsigned short* a1 = hb + (size_t)(hbase + c1) * Fn + lko;
  const unsigned short* Bt = w2T3 + (size_t)z * Dn * Fn;
  int n0 = nt * 128;
  const unsigned short* b0 = Bt + (size_t)(n0 + w * 32 + lr) * Fn + lko;
  gemm_core_p<4>(a0, a1, b0, b0 + 16 * Fn, Fn / 32, lA, lB, acc);
  const float* b2 = (z == 0) ? b2a : (z == 1) ? b2b : b2c;
#pragma unroll
  for (int i = 0; i < 4; ++i)
#pragma unroll
    for (int j = 0; j < 4; ++j)
#pragma unroll
      for (int r = 0; r < 4; ++r) {
        int row = m0 + wm + i * 16 + q * 4 + r;
        if (row < rows) {
          int tok = (z == 0) ? row : idx_m[(z - 1) * Mn + row];
          int col = n0 + wn + j * 16 + lm;
          atomicAdd(&outp[(size_t)tok * Dn + col], acc[i][j][r] + b2[col]);
        }
      }
}

// ---- pass B: general experts, group of 4 (z = 0..3, expert = g4+z) ----
__global__ __launch_bounds__(256) void k_fc1B(const unsigned short* __restrict__ ub,
                                              const unsigned short* __restrict__ w1Tg,
                                              const float* __restrict__ b1p,
                                              const int* __restrict__ cnt,
                                              const int* __restrict__ idx_g,
                                              const int* __restrict__ hbase_arr,
                                              unsigned short* __restrict__ hb, int g4) {
  int z = blockIdx.z;
  int e = g4 + z;
  int flat = blockIdx.x;
  int mt = flat & 31, nt = flat >> 5;
  int rows = cnt[e];
  int m0 = mt * 128;
  if (m0 >= rows) return;
  GEMM_PROLOG(4) GVARS(4)
  int r0 = m0 + w * 32 + lr, r1 = r0 + 16;
  int c0 = (r0 < rows) ? r0 : rows - 1;
  int c1 = (r1 < rows) ? r1 : rows - 1;
  int g0 = idx_g[e * Mn + c0];
  int g1 = idx_g[e * Mn + c1];
  const unsigned short* a0 = ub + (size_t)g0 * Dn + lko;
  const unsigned short* a1 = ub + (size_t)g1 * Dn + lko;
  const unsigned short* Bt = w1Tg + (size_t)z * Fn * Dn;
  int n0 = nt * 128;
  const unsigned short* b0 = Bt + (size_t)(n0 + w * 32 + lr) * Dn + lko;
  gemm_core_p<4>(a0, a1, b0, b0 + 16 * Dn, Dn / 32, lA, lB, acc);
  const float* bias = b1p + (size_t)(3 + e) * Fn;
  int hbase = hbase_arr[e];
#pragma unroll
  for (int i = 0; i < 4; ++i)
#pragma unroll
    for (int j = 0; j < 4; ++j)
#pragma unroll
      for (int r = 0; r < 4; ++r) {
        int row = m0 + wm + i * 16 + q * 4 + r;
        if (row < rows) {
          int col = n0 + wn + j * 16 + lm;
          float val = acc[i][j][r] + bias[col];
          val = 0.5f * val * (1.f + erff(val * 0.70710678118654752f));
          hb[(size_t)(hbase + row) * Fn + col] = f2bf(val);
        }
      }
}

__global__ __launch_bounds__(256) void k_fc2B(const unsigned short* __restrict__ hb,
                                              const unsigned short* __restrict__ w2Tg,
                                              const float* __restrict__ gen_b2,
                                              const int* __restrict__ cnt,
                                              const int* __restrict__ idx_g,
                                              const float* __restrict__ wt_g,
                                              const int* __restrict__ hbase_arr,
                                              float* __restrict__ outp, int g4) {
  int z = blockIdx.z;
  int e = g4 + z;
  int ks = blockIdx.y;               // split-K (2)
  int flat = blockIdx.x;
  int mt = flat & 31, nt = flat >> 5;
  int rows = cnt[e];
  int m0 = mt * 128;
  if (m0 >= rows) return;
  GEMM_PROLOG(4) GVARS(4)
  int hbase = hbase_arr[e];
  int koff = ks * (Fn / 2);
  int r0 = m0 + w * 32 + lr, r1 = r0 + 16;
  int c0 = (r0 < rows) ? r0 : rows - 1;
  int c1 = (r1 < rows) ? r1 : rows - 1;
  const unsigned short* a0 = hb + (size_t)(hbase + c0) * Fn + koff + lko;
  const unsigned short* a1 = hb + (size_t)(hbase + c1) * Fn + koff + lko;
  const unsigned short* Bt = w2Tg + (size_t)z * Dn * Fn;
  int n0 = nt * 128;
  const unsigned short* b0 = Bt + (size_t)(n0 + w * 32 + lr) * Fn + koff + lko;
  gemm_core_p<4>(a0, a1, b0, b0 + 16 * Fn, (Fn / 2) / 32, lA, lB, acc);
  const float* b2 = gen_b2 + (size_t)e * Dn;
#pragma unroll
  for (int i = 0; i < 4; ++i)
#pragma unroll
    for (int j = 0; j < 4; ++j)
#pragma unroll
      for (int r = 0; r < 4; ++r) {
        int row = m0 + wm + i * 16 + q * 4 + r;
        if (row < rows) {
          int tok = idx_g[e * Mn + row];
          float wtv = wt_g[e * Mn + row];
          int col = n0 + wn + j * 16 + lm;
          float val = acc[i][j][r] + (ks == 0 ? b2[col] : 0.f);
          atomicAdd(&outp[(size_t)tok * Dn + col], wtv * val);
        }
      }
}

// ---------- host ----------
extern "C" void kernel_launch(void* const* d_in, const int* in_sizes, int n_in,
                              void* d_out, int out_size, void* d_ws, size_t ws_size,
                              hipStream_t stream) {
  (void)in_sizes; (void)n_in; (void)out_size; (void)ws_size;
  const float* x       = (const float*)d_in[0];
  const int*   modality= (const int*)d_in[1];
  const float* n1g = (const float*)d_in[2];
  const float* n1b = (const float*)d_in[3];
  const float* n2g = (const float*)d_in[4];
  const float* n2b = (const float*)d_in[5];
  const float* Wq = (const float*)d_in[6];  const float* bq = (const float*)d_in[7];
  const float* Wk = (const float*)d_in[8];  const float* bk = (const float*)d_in[9];
  const float* Wv = (const float*)d_in[10]; const float* bv = (const float*)d_in[11];
  const float* Wo = (const float*)d_in[12]; const float* bo = (const float*)d_in[13];
  const float* Wr = (const float*)d_in[14]; const float* br = (const float*)d_in[15];
  const float* gen_lng = (const float*)d_in[16];
  const float* gen_lnb = (const float*)d_in[17];
  const float* gen_W1  = (const float*)d_in[18];
  const float* gen_b1  = (const float*)d_in[19];
  const float* gen_W2  = (const float*)d_in[20];
  const float* gen_b2  = (const float*)d_in[21];
  const float* ge_lng = (const float*)d_in[22]; const float* ge_lnb = (const float*)d_in[23];
  const float* ge_W1  = (const float*)d_in[24]; const float* ge_b1  = (const float*)d_in[25];
  const float* ge_W2  = (const float*)d_in[26]; const float* ge_b2  = (const float*)d_in[27];
  const float* ve_lng = (const float*)d_in[28]; const float* ve_lnb = (const float*)d_in[29];
  const float* ve_W1  = (const float*)d_in[30]; const float* ve_b1  = (const float*)d_in[31];
  const float* ve_W2  = (const float*)d_in[32]; const float* ve_b2  = (const float*)d_in[33];
  const float* te_lng = (const float*)d_in[34]; const float* te_lnb = (const float*)d_in[35];
  const float* te_W1  = (const float*)d_in[36]; const float* te_b1  = (const float*)d_in[37];
  const float* te_W2  = (const float*)d_in[38]; const float* te_b2  = (const float*)d_in[39];

  float* outp = (float*)d_out;

  char* wsp = (char*)d_ws;
  size_t off = 0;
  auto alloc = [&](size_t bytes) -> void* {
    void* p = wsp + off;
    off += (bytes + 255) & ~(size_t)255;
    return p;
  };
  // ---- persistent (live across both phases) ----
  unsigned short* ub   = (unsigned short*)alloc((size_t)Mn * Dn * 2);   // 8MB
  float*          b1p  = (float*)alloc((size_t)11 * Fn * 4);
  int*            idx_g= (int*)alloc((size_t)En * Mn * 4);
  float*          wt_g = (float*)alloc((size_t)En * Mn * 4);
  int*            idx_m= (int*)alloc((size_t)2 * Mn * 4);
  int*            cnt  = (int*)alloc(256);
  int*            offA = (int*)alloc(256);   // [0..2] pass-A hb bases
  int*            hbase= (int*)alloc(256);   // [0..7] pass-B hb bases
  char* arena = wsp + off;
  const size_t MB = 1024 * 1024;
  // ---- phase 1 (attention) layout in arena ----
  unsigned short* xn1 = (unsigned short*)(arena + 0);
  unsigned short* wqkT= (unsigned short*)(arena + 8 * MB);
  unsigned short* qb  = (unsigned short*)(arena + 16 * MB);
  unsigned short* kb  = (unsigned short*)(arena + 24 * MB);
  unsigned short* vb  = (unsigned short*)(arena + 32 * MB);
  unsigned short* attb= (unsigned short*)(arena + 40 * MB);
  unsigned short* ob  = (unsigned short*)(arena + 72 * MB);
  float*          x1  = (float*)(arena + 80 * MB);               // ends 96MB
  // ---- phase 2 (experts) layout in arena (reuses phase-1 space) ----
  unsigned short* wT3_1 = (unsigned short*)(arena + 0);          // 3x8MB
  unsigned short* wT3_2 = (unsigned short*)(arena + 24 * MB);    // 3x8MB
  unsigned short* w1Tg  = (unsigned short*)(arena + 48 * MB);    // 4x8MB
  unsigned short* w2Tg  = (unsigned short*)(arena + 80 * MB);    // 4x8MB
  unsigned short* hb    = (unsigned short*)(arena + 112 * MB);   // 8192 x 4096 bf16 = 64MB

  k_init<<<1, 64, 0, stream>>>(cnt);
  k_ln1<<<Mn, 256, 0, stream>>>(x, n1g, n1b, xn1);
  k_b1init<<<dim3(Fn / 256, 11), 256, 0, stream>>>(ge_b1, ve_b1, te_b1, gen_b1, b1p);

  P8 dummy{};
  {
    P8 wq{}; wq.p[0] = Wq; wq.p[1] = Wk; wq.p[2] = Wv; wq.p[3] = Wo;
    k_transpose<<<dim3(16, 16, 4), 256, 0, stream>>>(wq, dummy, dummy, 0, nullptr, 0,
                                                     wqkT, (size_t)Dn * Dn, Dn, Dn);
  }

  k_gemm_qkv<<<dim3(8, 32), 256, 0, stream>>>(xn1, wqkT,                       bq, qb, 0);
  k_gemm_qkv<<<dim3(8, 32), 256, 0, stream>>>(xn1, wqkT + (size_t)1 * Dn * Dn, bk, kb, 0);
  k_gemm_qkv<<<dim3(8, 32), 256, 0, stream>>>(xn1, wqkT + (size_t)2 * Dn * Dn, bv, vb, 1);

  for (int b = 0; b < Bn; ++b) {
    const unsigned short* qbb = qb + (size_t)b * Hn * Sn * HDn;
    const unsigned short* kbb = kb + (size_t)b * Hn * Sn * HDn;
    const unsigned short* vbb = vb + (size_t)b * Hn * HDn * Sn;
    k_scores<<<dim3(8, 8, Hn), 256, 0, stream>>>(qbb, kbb, attb);
    k_softmax<<<dim3(Sn, Hn), 256, 0, stream>>>(attb);
    k_meanatt<<<Sn * Sn / 256, 256, 0, stream>>>(attb, outp + MEANOFF + (size_t)b * Sn * Sn);
    k_av<<<dim3(1, 8, Hn), 256, 0, stream>>>(attb, vbb, ob, b);
  }

  k_ao<<<dim3(8, 32), 256, 0, stream>>>(ob, wqkT + (size_t)3 * Dn * Dn, bo, x, x1, outp);
  k_ln2<<<Mn, 256, 0, stream>>>(x1, n2g, n2b, Wr, br, ub, outp + LOGOFF, outp + PROBOFF,
                                cnt, idx_g, wt_g, idx_m, modality);
  k_finalize<<<1, 64, 0, stream>>>(cnt, offA, hbase);

  // ---- pass A: ge (dense) + ve/te (modality-routed) ----
  {
    P8 w1s{}, g1s{}, l1s{};
    w1s.p[0] = ge_W1; w1s.p[1] = ve_W1; w1s.p[2] = te_W1;
    g1s.p[0] = ge_lng; g1s.p[1] = ve_lng; g1s.p[2] = te_lng;
    l1s.p[0] = ge_lnb; l1s.p[1] = ve_lnb; l1s.p[2] = te_lnb;
    k_transpose<<<dim3(Fn / 64, Dn / 64, 3), 256, 0, stream>>>(w1s, g1s, l1s, 1, b1p, 0,
                                                               wT3_1, (size_t)Fn * Dn, Dn, Fn);
    P8 w2s{}; w2s.p[0] = ge_W2; w2s.p[1] = ve_W2; w2s.p[2] = te_W2;
    k_transpose<<<dim3(Dn / 64, Fn / 64, 3), 256, 0, stream>>>(w2s, dummy, dummy, 0, nullptr, 0,
                                                               wT3_2, (size_t)Dn * Fn, Fn, Dn);
    k_fc1A<<<dim3(1024, 1, 3), 256, 0, stream>>>(ub, wT3_1, b1p, cnt, idx_m, offA, hb);
    k_fc2A<<<dim3(256, 1, 3), 256, 0, stream>>>(hb, wT3_2, ge_b2, ve_b2, te_b2, cnt, idx_m, offA, outp);
  }

  // ---- pass B: general experts in 2 groups of 4 ----
  for (int g = 0; g < 2; ++g) {
    int g4 = g * 4;
    P8 w1s{}, g1s{}, l1s{}, w2s{};
    for (int z = 0; z < 4; ++z) {
      int e = g4 + z;
      w1s.p[z] = gen_W1 + (size_t)e * Dn * Fn;
      g1s.p[z] = gen_lng + (size_t)e * Dn;
      l1s.p[z] = gen_lnb + (size_t)e * Dn;
      w2s.p[z] = gen_W2 + (size_t)e * Fn * Dn;
    }
    k_transpose<<<dim3(Fn / 64, Dn / 64, 4), 256, 0, stream>>>(w1s, g1s, l1s, 1, b1p, 3 + g4,
                                                               w1Tg, (size_t)Fn * Dn, Dn, Fn);
    k_transpose<<<dim3(Dn / 64, Fn / 64, 4), 256, 0, stream>>>(w2s, dummy, dummy, 0, nullptr, 0,
                                                               w2Tg, (size_t)Dn * Fn, Fn, Dn);
    k_fc1B<<<dim3(1024, 1, 4), 256, 0, stream>>>(ub, w1Tg, b1p, cnt, idx_g, hbase, hb, g4);
    k_fc2B<<<dim3(256, 2, 4), 256, 0, stream>>>(hb, w2Tg, gen_b2, cnt, idx_g, wt_g, hbase, outp, g4);
  }
}

// Round 3
// 1425.340 us; speedup vs baseline: 1.9274x; 1.5542x over previous
//
#include <hip/hip_runtime.h>
#include <stdint.h>

// ---------- constants ----------
#define Bn 4
#define Sn 1024
#define Dn 1024
#define Fn 4096
#define En 8
#define Hn 16
#define HDn 64
#define Mn 4096           // B*S tokens
#define LOGOFF 4194304    // B*S*D
#define PROBOFF 4227072   // + B*S*E
#define MEANOFF 4259840   // + B*S*E
#define TA 66             // max tiles group A (ge 32 + ve/te <= 34)
#define TB 72             // max tiles group B (8 general, sum 8192 rows + pad)

typedef __attribute__((ext_vector_type(8))) short short8;
typedef __attribute__((ext_vector_type(4))) float f32x4;
typedef __attribute__((ext_vector_type(4))) unsigned short u16x4;
typedef __attribute__((ext_vector_type(8))) unsigned short u16x8;

#define DEV static __device__ __forceinline__

struct P8 { const float* p[8]; };
struct Tile { int eid; int base; int rows; int pad; };

DEV float bf2f(unsigned short u) {
  union { uint32_t i; float f; } x; x.i = ((uint32_t)u) << 16; return x.f;
}
DEV unsigned short f2bf(float f) {
  union { float f; uint32_t i; } x; x.f = f;
  uint32_t r = x.i + 0x7FFFu + ((x.i >> 16) & 1u);
  return (unsigned short)(r >> 16);
}

DEV void gl_lds16(const void* g, void* l) {
  __builtin_amdgcn_global_load_lds((const __attribute__((address_space(1))) void*)g,
                                   (__attribute__((address_space(3))) void*)l,
                                   16, 0, 0);
}

DEV float wsum(float v) { for (int o = 1; o < 64; o <<= 1) v += __shfl_xor(v, o); return v; }
DEV float wmaxr(float v) { for (int o = 1; o < 64; o <<= 1) v = fmaxf(v, __shfl_xor(v, o)); return v; }

DEV float block_sum(float v, float* sred, int t) {
  int w = t >> 6, l = t & 63;
  v = wsum(v);
  __syncthreads();
  if (l == 0) sred[w] = v;
  __syncthreads();
  return sred[0] + sred[1] + sred[2] + sred[3];
}
DEV float block_max(float v, float* sred, int t) {
  int w = t >> 6, l = t & 63;
  v = wmaxr(v);
  __syncthreads();
  if (l == 0) sred[w] = v;
  __syncthreads();
  return fmaxf(fmaxf(sred[0], sred[1]), fmaxf(sred[2], sred[3]));
}

// ---------- GEMM core (dense, per-lane row pointers advanced 32 bf16/iter) ----------
template<int JT>
DEV void gemm_core_p(const unsigned short* a0, const unsigned short* a1,
                     const unsigned short* b0, const unsigned short* b1,
                     int kiters, unsigned short* lA, unsigned short* lB, f32x4 (&acc)[4][JT]) {
  const int t = threadIdx.x, w = t >> 6, l = t & 63;
  const int wm = (w >> 1) * 64, wn = (w & 1) * (JT * 16);
  const int lm = l & 15, q = l >> 4;
  for (int it = 0; it < kiters; ++it) {
    gl_lds16(a0, lA + w * 1024);
    gl_lds16(a1, lA + w * 1024 + 512);
    if (JT == 4) {
      gl_lds16(b0, lB + w * 1024);
      gl_lds16(b1, lB + w * 1024 + 512);
      b1 += 32;
    } else {
      gl_lds16(b0, lB + w * 512);
    }
    a0 += 32; a1 += 32; b0 += 32;
    __syncthreads();
    short8 af[4], bfr[JT];
#pragma unroll
    for (int i = 0; i < 4; ++i) af[i] = *(const short8*)(lA + (wm + i * 16 + lm) * 32 + q * 8);
#pragma unroll
    for (int j = 0; j < JT; ++j) bfr[j] = *(const short8*)(lB + (wn + j * 16 + lm) * 32 + q * 8);
#pragma unroll
    for (int i = 0; i < 4; ++i)
#pragma unroll
      for (int j = 0; j < JT; ++j)
        acc[i][j] = __builtin_amdgcn_mfma_f32_16x16x32_bf16(af[i], bfr[j], acc[i][j], 0, 0, 0);
    __syncthreads();
  }
}

#define GEMM_PROLOG(JT)                                         \
  __shared__ __align__(16) unsigned short lA[128 * 32];         \
  __shared__ __align__(16) unsigned short lB[(JT) * 32 * 32];   \
  f32x4 acc[4][JT];                                             \
  _Pragma("unroll") for (int i = 0; i < 4; ++i)                 \
  _Pragma("unroll") for (int j = 0; j < (JT); ++j)              \
      acc[i][j] = (f32x4){0.f, 0.f, 0.f, 0.f};

#define GVARS(JT)                                               \
  const int t = threadIdx.x, w = t >> 6, l = t & 63;            \
  const int lr = l >> 2, lko = (l & 3) * 8;                     \
  const int wm = (w >> 1) * 64, wn = (w & 1) * ((JT) * 16);     \
  const int lm = l & 15, q = l >> 4;                            \
  (void)lr; (void)lko; (void)wm; (void)wn; (void)lm; (void)q;

// ---------- small kernels ----------

__global__ __launch_bounds__(64) void k_init(int* __restrict__ cnt) {
  if (threadIdx.x < 16) cnt[threadIdx.x] = 0;
}

// build tile tables (single thread; <=138 tiles)
__global__ __launch_bounds__(64) void k_finalize(const int* __restrict__ cnt,
                                                 Tile* __restrict__ tabA, int* __restrict__ ntA,
                                                 Tile* __restrict__ tabB, int* __restrict__ ntB) {
  if (threadIdx.x != 0) return;
  int n = 0;
  // group A: eid 0 = ge (dense 4096), 1 = ve (cnt[8]), 2 = te (cnt[9])
  for (int r0 = 0; r0 < Mn; r0 += 128) { tabA[n].eid = 0; tabA[n].base = r0; tabA[n].rows = 128; ++n; }
  for (int e = 1; e <= 2; ++e) {
    int c = cnt[7 + e];
    for (int r0 = 0; r0 < c; r0 += 128) {
      tabA[n].eid = e; tabA[n].base = r0; tabA[n].rows = (c - r0 < 128) ? c - r0 : 128; ++n;
    }
  }
  *ntA = n;
  n = 0;
  for (int g = 0; g < 8; ++g) {
    int c = cnt[g];
    for (int r0 = 0; r0 < c; r0 += 128) {
      tabB[n].eid = 3 + g; tabB[n].base = r0; tabB[n].rows = (c - r0 < 128) ? c - r0 : 128; ++n;
    }
  }
  *ntB = n;
}

// gather tokens into dense padded row space; also emit tok/wt per padded row
__global__ __launch_bounds__(256) void k_gather(const unsigned short* __restrict__ ub,
                                                const Tile* __restrict__ tab,
                                                const int* __restrict__ ntp,
                                                const int* __restrict__ idx_m,
                                                const int* __restrict__ idx_g,
                                                const float* __restrict__ wt_g,
                                                unsigned short* __restrict__ ua,
                                                int* __restrict__ tokArr,
                                                float* __restrict__ wtArr) {
  int row0 = blockIdx.x * 8;
  int tile = row0 >> 7;
  if (tile >= *ntp) return;
  Tile tl = tab[tile];
  int t = threadIdx.x;
  int half = t >> 7, lane = t & 127;
#pragma unroll
  for (int s = 0; s < 4; ++s) {
    int r = row0 + s * 2 + half;
    int local = r & 127;
    int tok = -1; float wt = 0.f;
    if (local < tl.rows) {
      int li = tl.base + local;
      if (tl.eid == 0) { tok = li; wt = 1.f; }
      else if (tl.eid <= 2) { tok = idx_m[(tl.eid - 1) * Mn + li]; wt = 1.f; }
      else { tok = idx_g[(tl.eid - 3) * Mn + li]; wt = wt_g[(tl.eid - 3) * Mn + li]; }
    }
    u16x8 v = (u16x8)0;
    if (tok >= 0) v = ((const u16x8*)(ub + (size_t)tok * Dn))[lane];
    ((u16x8*)(ua + (size_t)r * Dn))[lane] = v;
    if (lane == 0) { tokArr[r] = tok; wtArr[r] = wt; }
  }
}

// LN1: x -> bf16 normalized (n1 params)
__global__ __launch_bounds__(256) void k_ln1(const float* __restrict__ x,
                                             const float* __restrict__ g,
                                             const float* __restrict__ b,
                                             unsigned short* __restrict__ o) {
  __shared__ float sred[4];
  int row = blockIdx.x, t = threadIdx.x;
  f32x4 v = ((const f32x4*)(x + (size_t)row * Dn))[t];
  float m = block_sum(v.x + v.y + v.z + v.w, sred, t) * (1.f / Dn);
  f32x4 d = v - m;
  float var = block_sum(d.x * d.x + d.y * d.y + d.z * d.z + d.w * d.w, sred, t) * (1.f / Dn);
  float rs = rsqrtf(var + 1e-5f);
  f32x4 gg = ((const f32x4*)g)[t], bb = ((const f32x4*)b)[t];
  u16x4 r;
  r.x = f2bf(d.x * rs * gg.x + bb.x);
  r.y = f2bf(d.y * rs * gg.y + bb.y);
  r.z = f2bf(d.z * rs * gg.z + bb.z);
  r.w = f2bf(d.w * rs * gg.w + bb.w);
  *((u16x4*)(o + (size_t)row * Dn) + t) = r;
}

__global__ __launch_bounds__(256) void k_b1init(const float* __restrict__ ge,
                                                const float* __restrict__ ve,
                                                const float* __restrict__ te,
                                                const float* __restrict__ gen,
                                                float* __restrict__ b1p) {
  int e = blockIdx.y;
  int f = blockIdx.x * 256 + threadIdx.x;
  const float* src = (e == 0) ? ge : (e == 1) ? ve : (e == 2) ? te : gen + (size_t)(e - 3) * Fn;
  b1p[(size_t)e * Fn + f] = src[f];
}

// batched transpose: W[K][N] fp32 -> Wt[N][K] bf16 (z-th); optional LN fold
__global__ __launch_bounds__(256) void k_transpose(P8 Ws, P8 Gs, P8 Ls, int useGL,
                                                   float* __restrict__ b1p, int b1base,
                                                   unsigned short* __restrict__ Wt, size_t dstStride,
                                                   int K, int N) {
  __shared__ float tile[64][65];
  int z = blockIdx.z;
  const float* W = Ws.p[z];
  int n0 = blockIdx.x * 64, k0 = blockIdx.y * 64;
  int t = threadIdx.x, j = t & 63, i0 = t >> 6;
  const float* g = useGL ? Gs.p[z] : nullptr;
  const float* lnb = useGL ? Ls.p[z] : nullptr;
  float bsum = 0.f;
#pragma unroll 4
  for (int ii = 0; ii < 16; ++ii) {
    int i = i0 * 16 + ii;
    float wv = W[(size_t)(k0 + i) * N + n0 + j];
    if (useGL) { bsum += lnb[k0 + i] * wv; wv *= g[k0 + i]; }
    tile[i][j] = wv;
  }
  if (useGL) atomicAdd(&b1p[(size_t)(b1base + z) * Fn + n0 + j], bsum);
  __syncthreads();
  unsigned short* dst = Wt + (size_t)z * dstStride;
#pragma unroll 4
  for (int ii = 0; ii < 16; ++ii) {
    int i = i0 * 16 + ii;
    dst[(size_t)(n0 + i) * K + k0 + j] = f2bf(tile[j][i]);
  }
}

// fused QKV: out = xn1 @ [Wq|Wk|Wv] (N=3072), scatter per-mat layout
__global__ __launch_bounds__(256) void k_qkv(const unsigned short* __restrict__ A,
                                             const unsigned short* __restrict__ Bt,
                                             const float* __restrict__ bq,
                                             const float* __restrict__ bk,
                                             const float* __restrict__ bv,
                                             unsigned short* __restrict__ qb,
                                             unsigned short* __restrict__ kb,
                                             unsigned short* __restrict__ vb) {
  GEMM_PROLOG(4) GVARS(4)
  int m0 = blockIdx.y * 128, n0 = blockIdx.x * 128;
  int mat = n0 >> 10;                       // uniform per block (128 | 1024)
  const float* bias = (mat == 0) ? bq : (mat == 1) ? bk : bv;
  unsigned short* outb = (mat == 0) ? qb : (mat == 1) ? kb : vb;
  const unsigned short* a0 = A + (size_t)(m0 + w * 32 + lr) * Dn + lko;
  const unsigned short* b0 = Bt + (size_t)(n0 + w * 32 + lr) * Dn + lko;
  gemm_core_p<4>(a0, a0 + 16 * Dn, b0, b0 + 16 * Dn, Dn / 32, lA, lB, acc);
#pragma unroll
  for (int i = 0; i < 4; ++i)
#pragma unroll
    for (int j = 0; j < 4; ++j)
#pragma unroll
      for (int r = 0; r < 4; ++r) {
        int row = m0 + wm + i * 16 + q * 4 + r;
        int col = n0 + wn + j * 16 + lm;
        int cc = col & 1023;
        float val = acc[i][j][r] + bias[cc];
        int b = row >> 10, s = row & 1023, h = cc >> 6, d = cc & 63;
        size_t idx = (mat == 2) ? (((size_t)((b * Hn + h) * HDn + d)) << 10) + s
                                : ((size_t)((b * Hn + h) << 10) + s) * HDn + d;
        outb[idx] = f2bf(val);
      }
}

// scores for a half (2 batches): z = bh local (0..31)
__global__ __launch_bounds__(256) void k_scores(const unsigned short* __restrict__ qh,
                                                const unsigned short* __restrict__ kh,
                                                unsigned short* __restrict__ att) {
  GEMM_PROLOG(4) GVARS(4)
  int z = blockIdx.z;
  const unsigned short* A = qh + (size_t)z * Sn * HDn;
  const unsigned short* Bt = kh + (size_t)z * Sn * HDn;
  int m0 = blockIdx.y * 128, n0 = blockIdx.x * 128;
  const unsigned short* a0 = A + (size_t)(m0 + w * 32 + lr) * HDn + lko;
  const unsigned short* b0 = Bt + (size_t)(n0 + w * 32 + lr) * HDn + lko;
  gemm_core_p<4>(a0, a0 + 16 * HDn, b0, b0 + 16 * HDn, HDn / 32, lA, lB, acc);
#pragma unroll
  for (int i = 0; i < 4; ++i)
#pragma unroll
    for (int j = 0; j < 4; ++j)
#pragma unroll
      for (int r = 0; r < 4; ++r) {
        int row = m0 + wm + i * 16 + q * 4 + r;
        int col = n0 + wn + j * 16 + lm;
        att[((size_t)z << 20) + ((size_t)row << 10) + col] = f2bf(acc[i][j][r] * 0.125f);
      }
}

__global__ __launch_bounds__(256) void k_softmax(unsigned short* __restrict__ att) {
  __shared__ float sred[4];
  int t = threadIdx.x;
  size_t base = ((size_t)blockIdx.y << 20) + ((size_t)blockIdx.x << 10);
  u16x4 raw = *((u16x4*)(att + base) + t);
  float v0 = bf2f(raw.x), v1 = bf2f(raw.y), v2 = bf2f(raw.z), v3 = bf2f(raw.w);
  float mx = block_max(fmaxf(fmaxf(v0, v1), fmaxf(v2, v3)), sred, t);
  float e0 = expf(v0 - mx), e1 = expf(v1 - mx), e2 = expf(v2 - mx), e3 = expf(v3 - mx);
  float ssum = block_sum(e0 + e1 + e2 + e3, sred, t);
  float inv = 1.f / ssum;
  u16x4 r;
  r.x = f2bf(e0 * inv); r.y = f2bf(e1 * inv); r.z = f2bf(e2 * inv); r.w = f2bf(e3 * inv);
  *((u16x4*)(att + base) + t) = r;
}

// mean over heads for a half (2 batches)
__global__ __launch_bounds__(256) void k_meanatt(const unsigned short* __restrict__ att,
                                                 float* __restrict__ outm) {
  int g = blockIdx.x * 256 + threadIdx.x;      // 0 .. 2*S*S-1
  int bl = g >> 20, ss = g & 1048575;
  float s = 0.f;
#pragma unroll
  for (int h = 0; h < Hn; ++h) s += bf2f(att[((size_t)(bl * Hn + h) << 20) + ss]);
  outm[(size_t)bl * Sn * Sn + ss] = s * (1.f / Hn);
}

// o = att @ V for a half: z = bh local
__global__ __launch_bounds__(256) void k_av(const unsigned short* __restrict__ att,
                                            const unsigned short* __restrict__ vh,
                                            unsigned short* __restrict__ o, int half) {
  GEMM_PROLOG(2) GVARS(2)
  int z = blockIdx.z;
  int h = z & 15, bl = z >> 4;
  const unsigned short* A = att + ((size_t)z << 20);
  const unsigned short* Bt = vh + (size_t)z * HDn * Sn;
  int m0 = blockIdx.y * 128;
  const unsigned short* a0 = A + (size_t)(m0 + w * 32 + lr) * Sn + lko;
  const unsigned short* b0 = Bt + (size_t)(w * 16 + lr) * Sn + lko;
  gemm_core_p<2>(a0, a0 + 16 * Sn, b0, b0, Sn / 32, lA, lB, acc);
  int btok = (half * 2 + bl) << 10;
#pragma unroll
  for (int i = 0; i < 4; ++i)
#pragma unroll
    for (int j = 0; j < 2; ++j)
#pragma unroll
      for (int r = 0; r < 4; ++r) {
        int row = m0 + wm + i * 16 + q * 4 + r;
        int col = wn + j * 16 + lm;
        o[((size_t)(btok + row)) * Dn + h * HDn + col] = f2bf(acc[i][j][r]);
      }
}

// x1 = x + o @ Wo + bo ; also d_out = x1
__global__ __launch_bounds__(256) void k_ao(const unsigned short* __restrict__ A,
                                            const unsigned short* __restrict__ Bt,
                                            const float* __restrict__ bo,
                                            const float* __restrict__ x,
                                            float* __restrict__ x1,
                                            float* __restrict__ outp) {
  GEMM_PROLOG(4) GVARS(4)
  int m0 = blockIdx.y * 128, n0 = blockIdx.x * 128;
  const unsigned short* a0 = A + (size_t)(m0 + w * 32 + lr) * Dn + lko;
  const unsigned short* b0 = Bt + (size_t)(n0 + w * 32 + lr) * Dn + lko;
  gemm_core_p<4>(a0, a0 + 16 * Dn, b0, b0 + 16 * Dn, Dn / 32, lA, lB, acc);
#pragma unroll
  for (int i = 0; i < 4; ++i)
#pragma unroll
    for (int j = 0; j < 4; ++j)
#pragma unroll
      for (int r = 0; r < 4; ++r) {
        int row = m0 + wm + i * 16 + q * 4 + r;
        int col = n0 + wn + j * 16 + lm;
        size_t idx = (size_t)row * Dn + col;
        float val = acc[i][j][r] + bo[col] + x[idx];
        x1[idx] = val;
        outp[idx] = val;
      }
}

// LN2 + inner-expert normalize + router + routing lists
__global__ __launch_bounds__(256) void k_ln2(const float* __restrict__ x1,
                                             const float* __restrict__ g,
                                             const float* __restrict__ b,
                                             const float* __restrict__ Wr,
                                             const float* __restrict__ br,
                                             unsigned short* __restrict__ ubuf,
                                             float* __restrict__ logits_out,
                                             float* __restrict__ probs_out,
                                             int* __restrict__ cnt,
                                             int* __restrict__ idx_g,
                                             float* __restrict__ wt_g,
                                             int* __restrict__ idx_m,
                                             const int* __restrict__ modality) {
  __shared__ float sred[4];
  __shared__ float lred[4][En];
  int row = blockIdx.x, t = threadIdx.x;
  f32x4 v = ((const f32x4*)(x1 + (size_t)row * Dn))[t];
  float m1 = block_sum(v.x + v.y + v.z + v.w, sred, t) * (1.f / Dn);
  f32x4 d = v - m1;
  float var1 = block_sum(d.x * d.x + d.y * d.y + d.z * d.z + d.w * d.w, sred, t) * (1.f / Dn);
  float rs1 = rsqrtf(var1 + 1e-5f);
  f32x4 gg = ((const f32x4*)g)[t], bb = ((const f32x4*)b)[t];
  f32x4 xn = d * rs1 * gg + bb;
  float m2 = block_sum(xn.x + xn.y + xn.z + xn.w, sred, t) * (1.f / Dn);
  f32x4 d2 = xn - m2;
  float var2 = block_sum(d2.x * d2.x + d2.y * d2.y + d2.z * d2.z + d2.w * d2.w, sred, t) * (1.f / Dn);
  float rs2 = rsqrtf(var2 + 1e-5f);
  u16x4 r;
  r.x = f2bf(d2.x * rs2); r.y = f2bf(d2.y * rs2);
  r.z = f2bf(d2.z * rs2); r.w = f2bf(d2.w * rs2);
  *((u16x4*)(ubuf + (size_t)row * Dn) + t) = r;
  float lacc[En];
#pragma unroll
  for (int e = 0; e < En; ++e) lacc[e] = 0.f;
  int d0 = t * 4;
#pragma unroll
  for (int c = 0; c < 4; ++c) {
    const float* wr = Wr + (size_t)(d0 + c) * En;
    float xv = xn[c];
#pragma unroll
    for (int e = 0; e < En; ++e) lacc[e] += xv * wr[e];
  }
#pragma unroll
  for (int e = 0; e < En; ++e) lacc[e] = wsum(lacc[e]);
  __syncthreads();
  if ((t & 63) == 0)
#pragma unroll
    for (int e = 0; e < En; ++e) lred[t >> 6][e] = lacc[e];
  __syncthreads();
  if (t == 0) {
    float lg[En];
#pragma unroll
    for (int e = 0; e < En; ++e)
      lg[e] = lred[0][e] + lred[1][e] + lred[2][e] + lred[3][e] + br[e];
    for (int e = 0; e < En; ++e) logits_out[(size_t)row * En + e] = lg[e];
    float mx = lg[0];
    for (int e = 1; e < En; ++e) mx = fmaxf(mx, lg[e]);
    float pe[En], ssum = 0.f;
    for (int e = 0; e < En; ++e) { pe[e] = expf(lg[e] - mx); ssum += pe[e]; }
    float inv = 1.f / ssum;
    float pr[En];
    for (int e = 0; e < En; ++e) { pr[e] = pe[e] * inv; probs_out[(size_t)row * En + e] = pr[e]; }
    int i0 = 0;
    for (int e = 1; e < En; ++e) if (pr[e] > pr[i0]) i0 = e;
    int i1 = (i0 == 0) ? 1 : 0;
    for (int e = 0; e < En; ++e) if (e != i0 && pr[e] > pr[i1]) i1 = e;
    float ee = expf(pr[i1] - pr[i0]);
    float w0 = 1.f / (1.f + ee), w1 = ee / (1.f + ee);
    int p0 = atomicAdd(&cnt[i0], 1);
    idx_g[i0 * Mn + p0] = row; wt_g[i0 * Mn + p0] = w0;
    int p1 = atomicAdd(&cnt[i1], 1);
    idx_g[i1 * Mn + p1] = row; wt_g[i1 * Mn + p1] = w1;
    int md = modality[row];
    int pm = atomicAdd(&cnt[8 + md], 1);
    idx_m[md * Mn + pm] = row;
  }
}

// dense fc1 over padded tile space: grid (nt=32, tile)
__global__ __launch_bounds__(256) void k_fc1(const unsigned short* __restrict__ ua,
                                             const unsigned short* __restrict__ w1T,
                                             const float* __restrict__ b1p,
                                             const Tile* __restrict__ tab,
                                             const int* __restrict__ ntp,
                                             int eidOff,
                                             unsigned short* __restrict__ hb) {
  int tile = blockIdx.y;
  if (tile >= *ntp) return;
  Tile tl = tab[tile];
  GEMM_PROLOG(4) GVARS(4)
  int n0 = blockIdx.x * 128;
  const unsigned short* a0 = ua + (size_t)(tile * 128 + w * 32 + lr) * Dn + lko;
  const unsigned short* Bt = w1T + (size_t)(tl.eid - eidOff) * Fn * Dn;
  const unsigned short* b0 = Bt + (size_t)(n0 + w * 32 + lr) * Dn + lko;
  gemm_core_p<4>(a0, a0 + 16 * Dn, b0, b0 + 16 * Dn, Dn / 32, lA, lB, acc);
  const float* bias = b1p + (size_t)tl.eid * Fn;
#pragma unroll
  for (int i = 0; i < 4; ++i)
#pragma unroll
    for (int j = 0; j < 4; ++j)
#pragma unroll
      for (int r = 0; r < 4; ++r) {
        int row = tile * 128 + wm + i * 16 + q * 4 + r;
        int col = n0 + wn + j * 16 + lm;
        float val = acc[i][j][r] + bias[col];
        val = 0.5f * val * (1.f + erff(val * 0.70710678118654752f));
        hb[(size_t)row * Fn + col] = f2bf(val);
      }
}

// dense fc2 + scatter: grid (nt=8, tile)
__global__ __launch_bounds__(256) void k_fc2(const unsigned short* __restrict__ hb,
                                             const unsigned short* __restrict__ w2T,
                                             P8 b2s,
                                             const Tile* __restrict__ tab,
                                             const int* __restrict__ ntp,
                                             int eidOff,
                                             const int* __restrict__ tokArr,
                                             const float* __restrict__ wtArr,
                                             float* __restrict__ outp) {
  int tile = blockIdx.y;
  if (tile >= *ntp) return;
  Tile tl = tab[tile];
  GEMM_PROLOG(4) GVARS(4)
  int n0 = blockIdx.x * 128;
  const unsigned short* a0 = hb + (size_t)(tile * 128 + w * 32 + lr) * Fn + lko;
  const unsigned short* Bt = w2T + (size_t)(tl.eid - eidOff) * Dn * Fn;
  const unsigned short* b0 = Bt + (size_t)(n0 + w * 32 + lr) * Fn + lko;
  gemm_core_p<4>(a0, a0 + 16 * Fn, b0, b0 + 16 * Fn, Fn / 32, lA, lB, acc);
  const float* b2 = b2s.p[tl.eid - eidOff];
#pragma unroll
  for (int i = 0; i < 4; ++i)
#pragma unroll
    for (int j = 0; j < 4; ++j)
#pragma unroll
      for (int r = 0; r < 4; ++r) {
        int row = tile * 128 + wm + i * 16 + q * 4 + r;
        int tok = tokArr[row];
        if (tok >= 0) {
          float wt = wtArr[row];
          int col = n0 + wn + j * 16 + lm;
          atomicAdd(&outp[(size_t)tok * Dn + col], wt * (acc[i][j][r] + b2[col]));
        }
      }
}

// ---------- host ----------
extern "C" void kernel_launch(void* const* d_in, const int* in_sizes, int n_in,
                              void* d_out, int out_size, void* d_ws, size_t ws_size,
                              hipStream_t stream) {
  (void)in_sizes; (void)n_in; (void)out_size; (void)ws_size;
  const float* x       = (const float*)d_in[0];
  const int*   modality= (const int*)d_in[1];
  const float* n1g = (const float*)d_in[2];
  const float* n1b = (const float*)d_in[3];
  const float* n2g = (const float*)d_in[4];
  const float* n2b = (const float*)d_in[5];
  const float* Wq = (const float*)d_in[6];  const float* bq = (const float*)d_in[7];
  const float* Wk = (const float*)d_in[8];  const float* bk = (const float*)d_in[9];
  const float* Wv = (const float*)d_in[10]; const float* bv = (const float*)d_in[11];
  const float* Wo = (const float*)d_in[12]; const float* bo = (const float*)d_in[13];
  const float* Wr = (const float*)d_in[14]; const float* br = (const float*)d_in[15];
  const float* gen_lng = (const float*)d_in[16];
  const float* gen_lnb = (const float*)d_in[17];
  const float* gen_W1  = (const float*)d_in[18];
  const float* gen_b1  = (const float*)d_in[19];
  const float* gen_W2  = (const float*)d_in[20];
  const float* gen_b2  = (const float*)d_in[21];
  const float* ge_lng = (const float*)d_in[22]; const float* ge_lnb = (const float*)d_in[23];
  const float* ge_W1  = (const float*)d_in[24]; const float* ge_b1  = (const float*)d_in[25];
  const float* ge_W2  = (const float*)d_in[26]; const float* ge_b2  = (const float*)d_in[27];
  const float* ve_lng = (const float*)d_in[28]; const float* ve_lnb = (const float*)d_in[29];
  const float* ve_W1  = (const float*)d_in[30]; const float* ve_b1  = (const float*)d_in[31];
  const float* ve_W2  = (const float*)d_in[32]; const float* ve_b2  = (const float*)d_in[33];
  const float* te_lng = (const float*)d_in[34]; const float* te_lnb = (const float*)d_in[35];
  const float* te_W1  = (const float*)d_in[36]; const float* te_b1  = (const float*)d_in[37];
  const float* te_W2  = (const float*)d_in[38]; const float* te_b2  = (const float*)d_in[39];

  float* outp = (float*)d_out;

  char* wsp = (char*)d_ws;
  size_t off = 0;
  auto alloc = [&](size_t bytes) -> void* {
    void* p = wsp + off;
    off += (bytes + 255) & ~(size_t)255;
    return p;
  };
  // ---- persistent ----
  unsigned short* ub    = (unsigned short*)alloc((size_t)Mn * Dn * 2);     // 8MB
  float*          b1p   = (float*)alloc((size_t)11 * Fn * 4);
  int*            idx_g = (int*)alloc((size_t)En * Mn * 4);
  float*          wt_g  = (float*)alloc((size_t)En * Mn * 4);
  int*            idx_m = (int*)alloc((size_t)2 * Mn * 4);
  int*            cnt   = (int*)alloc(256);
  int*            ntAB  = (int*)alloc(256);              // [0]=ntA [1]=ntB
  Tile*           tabA  = (Tile*)alloc(sizeof(Tile) * TA);
  Tile*           tabB  = (Tile*)alloc(sizeof(Tile) * TB);
  int*            tokA  = (int*)alloc((size_t)TA * 128 * 4);
  float*          wtA   = (float*)alloc((size_t)TA * 128 * 4);
  int*            tokB  = (int*)alloc((size_t)TB * 128 * 4);
  float*          wtB   = (float*)alloc((size_t)TB * 128 * 4);
  char* arena = wsp + ((off + 1048575) & ~(size_t)1048575);
  const size_t MB = 1024 * 1024;
  // phase 1
  unsigned short* xn1 = (unsigned short*)(arena + 0);
  unsigned short* wqkT= (unsigned short*)(arena + 8 * MB);    // q,k,v,o transposed (4x2MB)
  unsigned short* qb  = (unsigned short*)(arena + 16 * MB);
  unsigned short* kb  = (unsigned short*)(arena + 24 * MB);
  unsigned short* vb  = (unsigned short*)(arena + 32 * MB);
  unsigned short* attb= (unsigned short*)(arena + 40 * MB);   // 64MB (half: 2 batches x 16 heads)
  unsigned short* ob  = (unsigned short*)(arena + 104 * MB);
  float*          x1  = (float*)(arena + 112 * MB);           // ends 128MB
  // phase 2A
  unsigned short* wTA = (unsigned short*)(arena + 0);         // 24MB (W1 then W2)
  unsigned short* uaA = (unsigned short*)(arena + 24 * MB);   // 17MB
  unsigned short* hbA = (unsigned short*)(arena + 48 * MB);   // 66MB
  // phase 2B
  unsigned short* wTB = (unsigned short*)(arena + 0);         // 64MB
  unsigned short* uaB = (unsigned short*)(arena + 64 * MB);   // 18MB
  unsigned short* hbB = (unsigned short*)(arena + 88 * MB);   // 72MB -> ends 160MB

  k_init<<<1, 64, 0, stream>>>(cnt);
  k_ln1<<<Mn, 256, 0, stream>>>(x, n1g, n1b, xn1);
  k_b1init<<<dim3(Fn / 256, 11), 256, 0, stream>>>(ge_b1, ve_b1, te_b1, gen_b1, b1p);

  P8 dummy{};
  {
    P8 wq{}; wq.p[0] = Wq; wq.p[1] = Wk; wq.p[2] = Wv; wq.p[3] = Wo;
    k_transpose<<<dim3(16, 16, 4), 256, 0, stream>>>(wq, dummy, dummy, 0, nullptr, 0,
                                                     wqkT, (size_t)Dn * Dn, Dn, Dn);
  }
  k_qkv<<<dim3(24, 32), 256, 0, stream>>>(xn1, wqkT, bq, bk, bv, qb, kb, vb);

  for (int half = 0; half < 2; ++half) {
    const unsigned short* qh = qb + (size_t)half * 2 * Hn * Sn * HDn;
    const unsigned short* kh = kb + (size_t)half * 2 * Hn * Sn * HDn;
    const unsigned short* vh = vb + (size_t)half * 2 * Hn * HDn * Sn;
    k_scores<<<dim3(8, 8, 32), 256, 0, stream>>>(qh, kh, attb);
    k_softmax<<<dim3(Sn, 32), 256, 0, stream>>>(attb);
    k_meanatt<<<2 * Sn * Sn / 256, 256, 0, stream>>>(attb, outp + MEANOFF + (size_t)half * 2 * Sn * Sn);
    k_av<<<dim3(1, 8, 32), 256, 0, stream>>>(attb, vh, ob, half);
  }

  k_ao<<<dim3(8, 32), 256, 0, stream>>>(ob, wqkT + (size_t)3 * Dn * Dn, bo, x, x1, outp);
  k_ln2<<<Mn, 256, 0, stream>>>(x1, n2g, n2b, Wr, br, ub, outp + LOGOFF, outp + PROBOFF,
                                cnt, idx_g, wt_g, idx_m, modality);
  k_finalize<<<1, 64, 0, stream>>>(cnt, tabA, ntAB, tabB, ntAB + 1);

  // ---- group A: ge, ve, te ----
  {
    P8 w1s{}, g1s{}, l1s{};
    w1s.p[0] = ge_W1; w1s.p[1] = ve_W1; w1s.p[2] = te_W1;
    g1s.p[0] = ge_lng; g1s.p[1] = ve_lng; g1s.p[2] = te_lng;
    l1s.p[0] = ge_lnb; l1s.p[1] = ve_lnb; l1s.p[2] = te_lnb;
    k_transpose<<<dim3(Fn / 64, Dn / 64, 3), 256, 0, stream>>>(w1s, g1s, l1s, 1, b1p, 0,
                                                               wTA, (size_t)Fn * Dn, Dn, Fn);
    k_gather<<<TA * 16, 256, 0, stream>>>(ub, tabA, ntAB, idx_m, idx_g, wt_g, uaA, tokA, wtA);
    k_fc1<<<dim3(32, TA), 256, 0, stream>>>(uaA, wTA, b1p, tabA, ntAB, 0, hbA);
    P8 w2s{}; w2s.p[0] = ge_W2; w2s.p[1] = ve_W2; w2s.p[2] = te_W2;
    k_transpose<<<dim3(Dn / 64, Fn / 64, 3), 256, 0, stream>>>(w2s, dummy, dummy, 0, nullptr, 0,
                                                               wTA, (size_t)Dn * Fn, Fn, Dn);
    P8 b2s{}; b2s.p[0] = ge_b2; b2s.p[1] = ve_b2; b2s.p[2] = te_b2;
    k_fc2<<<dim3(8, TA), 256, 0, stream>>>(hbA, wTA, b2s, tabA, ntAB, 0, tokA, wtA, outp);
  }

  // ---- group B: 8 general experts ----
  {
    P8 w1s{}, g1s{}, l1s{};
    for (int e = 0; e < 8; ++e) {
      w1s.p[e] = gen_W1 + (size_t)e * Dn * Fn;
      g1s.p[e] = gen_lng + (size_t)e * Dn;
      l1s.p[e] = gen_lnb + (size_t)e * Dn;
    }
    k_transpose<<<dim3(Fn / 64, Dn / 64, 8), 256, 0, stream>>>(w1s, g1s, l1s, 1, b1p, 3,
                                                               wTB, (size_t)Fn * Dn, Dn, Fn);
    k_gather<<<TB * 16, 256, 0, stream>>>(ub, tabB, ntAB + 1, idx_m, idx_g, wt_g, uaB, tokB, wtB);
    k_fc1<<<dim3(32, TB), 256, 0, stream>>>(uaB, wTB, b1p, tabB, ntAB + 1, 3, hbB);
    P8 w2s{};
    for (int e = 0; e < 8; ++e) w2s.p[e] = gen_W2 + (size_t)e * Fn * Dn;
    k_transpose<<<dim3(Dn / 64, Fn / 64, 8), 256, 0, stream>>>(w2s, dummy, dummy, 0, nullptr, 0,
                                                               wTB, (size_t)Dn * Fn, Fn, Dn);
    P8 b2s{};
    for (int e = 0; e < 8; ++e) b2s.p[e] = gen_b2 + (size_t)e * Dn;
    k_fc2<<<dim3(8, TB), 256, 0, stream>>>(hbB, wTB, b2s, tabB, ntAB + 1, 3, tokB, wtB, outp);
  }
}